// Round 10
// baseline (198.624 us; speedup 1.0000x reference)
//
#include <hip/hip_runtime.h>

typedef _Float16 f16;
typedef f16   f16x4 __attribute__((ext_vector_type(4)));
typedef f16   f16x8 __attribute__((ext_vector_type(8)));
typedef float f32x4 __attribute__((ext_vector_type(4)));

#define MFMA16(a, b, c) __builtin_amdgcn_mfma_f32_16x16x32_f16((a), (b), (c), 0, 0, 0)

// ---- weight images in d_ws (f16 units). granule = [64n][64k^swz] = 4096 f16 = 8KB ----
#define IMG_W1   0        // 4 pairs: pair kq = {granule(kq,n0..63), granule(kq,n64..127)}
#define IMG_W2   32768    // {w2 kh0, w2 kh1}
#define IMG_GW1  40960    // [32n][64k] = 2048
#define IMG_E    43008    // per e (16384): half h at +h*8192 = {ew1[e] colhalf h, ew2[e] rowhalf h}
#define IMG_SWH  108544   // {sw (4096), hw1[0] (2048), hw1[1] (2048)}
#define IMG_HW2G 116736   // hw1[2] (2048)

__device__ __forceinline__ float silu_f(float v) {
    return v * __builtin_amdgcn_rcpf(1.0f + __expf(-v));
}

// ============ prep: fp32 src[K][N] block -> f16 granule [n][k ^ ((n&7)<<3)] ============
__device__ void conv_blk(const float* __restrict__ src, f16* __restrict__ dst,
                         int srcN, int k0, int n0, int KB, int NB, int tid, int nth) {
    for (int i = tid; i < KB * NB; i += nth) {
        const int kk = i / NB, nn = i - kk * NB;
        dst[nn * KB + (kk ^ ((nn & 7) << 3))] = (f16)src[(long)(k0 + kk) * srcN + n0 + nn];
    }
}

__global__ void prep_weights(const float* __restrict__ w1, const float* __restrict__ w2,
                             const float* __restrict__ gw1, const float* __restrict__ ew1,
                             const float* __restrict__ ew2, const float* __restrict__ sw,
                             const float* __restrict__ hw1, f16* __restrict__ ws) {
    const int tid = blockIdx.x * 256 + threadIdx.x;
    const int nth = gridDim.x * 256;
    for (int kq = 0; kq < 4; ++kq)
        for (int nh = 0; nh < 2; ++nh)
            conv_blk(w1, ws + IMG_W1 + (kq * 2 + nh) * 4096, 128, kq * 64, nh * 64, 64, 64, tid, nth);
    for (int kh = 0; kh < 2; ++kh)
        conv_blk(w2, ws + IMG_W2 + kh * 4096, 64, kh * 64, 0, 64, 64, tid, nth);
    conv_blk(gw1, ws + IMG_GW1, 32, 0, 0, 64, 32, tid, nth);
    for (int e = 0; e < 4; ++e)
        for (int h = 0; h < 2; ++h) {
            conv_blk(ew1 + e * 8192, ws + IMG_E + e * 16384 + h * 8192,        128, 0, h * 64, 64, 64, tid, nth);
            conv_blk(ew2 + e * 8192, ws + IMG_E + e * 16384 + h * 8192 + 4096,  64, h * 64, 0, 64, 64, tid, nth);
        }
    conv_blk(sw, ws + IMG_SWH, 64, 0, 0, 64, 64, tid, nth);
    for (int h = 0; h < 2; ++h)
        conv_blk(hw1 + h * 2048, ws + IMG_SWH + 4096 + h * 2048, 32, 0, 0, 64, 32, tid, nth);
    conv_blk(hw1 + 2 * 2048, ws + IMG_HW2G, 32, 0, 0, 64, 32, tid, nth);
}

// ============ fragment access ============
// Weight granules read DIRECTLY from global (pre-swizzled image; L1/L2-resident).
__device__ __forceinline__ int swzW(int n) { return (n & 7) << 3; }
__device__ __forceinline__ int swzS(int r) { return (((((r >> 2) & 3) << 1) | (r & 1))) << 3; }

__device__ __forceinline__ f16x8 ldW(const f16* __restrict__ base, int row_base, int k0, int lane) {
    const int r = row_base + (lane & 15);
    const int k = k0 + ((lane >> 4) << 3);
    return *(const f16x8*)(base + r * 64 + (k ^ swzW(r)));
}
__device__ __forceinline__ f16x8 ldS(const f16* strip, int k0, int lane) {
    const int r = lane & 15;
    const int k = k0 + ((lane >> 4) << 3);
    return *(const f16x8*)(strip + r * 64 + (k ^ swzS(r)));
}
__device__ __forceinline__ void stS(f16* strip, int col_base, f32x4 v, int lane) {
    const int cc = col_base + (lane & 15);
    #pragma unroll
    for (int g = 0; g < 4; ++g) {
        const int r = ((lane >> 4) << 2) + g;
        strip[r * 64 + (cc ^ swzS(r))] = (f16)v[g];
    }
}

// 8 MFMAs: acc[4] += A[2] @ granule (M=16 rows); B-frags streamed from global
__device__ __forceinline__ void mm8(const f16x8 a[2], const f16* __restrict__ wb, f32x4 acc[4], int lane) {
    #pragma unroll
    for (int ks = 0; ks < 2; ++ks)
        #pragma unroll
        for (int n = 0; n < 4; ++n) {
            const f16x8 b = ldW(wb, n * 16, ks * 32, lane);
            acc[n] = MFMA16(a[ks], b, acc[n]);
        }
}

// silu(acc) -> strip -> A-frags
__device__ __forceinline__ void silu_to_frags(f16* strip, const f32x4 in[4], f16x8 outf[2], int lane) {
    #pragma unroll
    for (int n = 0; n < 4; ++n) {
        f32x4 v;
        #pragma unroll
        for (int g = 0; g < 4; ++g) v[g] = silu_f(in[n][g]);
        stS(strip, n * 16, v, lane);
    }
    #pragma unroll
    for (int ks = 0; ks < 2; ++ks)
        outf[ks] = ldS(strip, ks * 32, lane);
}

__device__ __forceinline__ f32x4 reduce16(f32x4 v) {
    #pragma unroll
    for (int m = 1; m <= 8; m <<= 1) {
        f32x4 o;
        #pragma unroll
        for (int i = 0; i < 4; ++i) o[i] = __shfl_xor(v[i], m, 64);
        v += o;
    }
    return v;
}

__global__ __launch_bounds__(256, 6)
void fused_net_mfma(const float* __restrict__ x,   const f16* __restrict__ wsp,
                    const float* __restrict__ b1,  const float* __restrict__ lng,
                    const float* __restrict__ lnb, const float* __restrict__ b2,
                    const float* __restrict__ eb1, const float* __restrict__ eb2,
                    const float* __restrict__ gb1, const float* __restrict__ gw2,
                    const float* __restrict__ gb2, const float* __restrict__ sb,
                    const float* __restrict__ hb1, const float* __restrict__ hw2,
                    const float* __restrict__ hb2, float* __restrict__ out)
{
    // 8.5 KB LDS: per-wave strips + per-wave gate weights. ZERO barriers in kernel.
    __shared__ __align__(16) f16 lds[4352];
    const int lane = threadIdx.x & 63;
    const int wv   = threadIdx.x >> 6;
    const int c    = lane & 15;
    const int q    = lane >> 4;
    f16* STRIP = lds + wv * 1024;               // per-wave [16][64]
    f16* const GWT = lds + 4096;                // [wv][e][16 rows] f16

    const long blockRow = (long)blockIdx.x * 64;
    const float* xw = x + (blockRow + wv * 16) * 256;   // this wave's 16 rows

    // ================= stem1: acc = x @ w1 + b1 (4 k-quarters) =================
    f32x4 acc[8];
    #pragma unroll
    for (int n8 = 0; n8 < 8; ++n8) {
        const float bv = b1[n8 * 16 + c];
        f32x4 t = {bv, bv, bv, bv};
        acc[n8] = t;
    }

    #pragma unroll 1
    for (int kq = 0; kq < 4; ++kq) {
        // x quarter kq -> strip (coalesced float4, transient regs)
        #pragma unroll
        for (int i = 0; i < 4; ++i) {
            const int idx4 = lane + i * 64;
            const int r  = idx4 >> 4;
            const int c4 = (idx4 & 15) << 2;
            const float4 v = *(const float4*)(xw + r * 256 + kq * 64 + c4);
            f16x4 o; o[0] = (f16)v.x; o[1] = (f16)v.y; o[2] = (f16)v.z; o[3] = (f16)v.w;
            *(f16x4*)(STRIP + r * 64 + (c4 ^ swzS(r))) = o;
        }
        f16x8 af[2];
        #pragma unroll
        for (int ks = 0; ks < 2; ++ks)
            af[ks] = ldS(STRIP, ks * 32, lane);

        mm8(af, wsp + IMG_W1 + kq * 8192,        acc,     lane);   // N 0..63
        mm8(af, wsp + IMG_W1 + kq * 8192 + 4096, acc + 4, lane);   // N 64..127
    }

    // ---- LN stats (registers only) ----
    f32x4 mu, rs;
    {
        f32x4 s = {0,0,0,0}, qq = {0,0,0,0};
        #pragma unroll
        for (int n8 = 0; n8 < 8; ++n8) { s += acc[n8]; qq += acc[n8] * acc[n8]; }
        s = reduce16(s); qq = reduce16(qq);
        mu = s * 0.0078125f;
        #pragma unroll
        for (int g = 0; g < 4; ++g)
            rs[g] = rsqrtf(qq[g] * 0.0078125f - mu[g] * mu[g] + 1e-5f);
    }

    // ================= stem2: hb = silu(LN @ w2 + b2) =================
    f32x4 a2[4];
    #pragma unroll
    for (int n = 0; n < 4; ++n) {
        const float bv = b2[n * 16 + c];
        f32x4 t = {bv, bv, bv, bv};
        a2[n] = t;
    }
    #pragma unroll
    for (int kh = 0; kh < 2; ++kh) {
        #pragma unroll
        for (int n = 0; n < 4; ++n) {
            const int j = kh * 64 + n * 16 + c;
            const float gg = lng[j], bb = lnb[j];
            f32x4 v;
            #pragma unroll
            for (int g = 0; g < 4; ++g)
                v[g] = silu_f((acc[kh * 4 + n][g] - mu[g]) * rs[g] * gg + bb);
            stS(STRIP, n * 16, v, lane);
        }
        f16x8 af[2];
        #pragma unroll
        for (int ks = 0; ks < 2; ++ks)
            af[ks] = ldS(STRIP, ks * 32, lane);
        mm8(af, wsp + IMG_W2 + kh * 4096, a2, lane);
    }
    // hb -> A-frags (8 VGPRs, held through experts)
    f16x8 hbA[2];
    silu_to_frags(STRIP, a2, hbA, lane);

    // ---- gate -> GWT (per-wave LDS) ----
    {
        f32x4 ag[2];
        #pragma unroll
        for (int n = 0; n < 2; ++n) {
            const float bv = gb1[n * 16 + c];
            f32x4 t = {bv, bv, bv, bv};
            ag[n] = t;
        }
        #pragma unroll
        for (int ks = 0; ks < 2; ++ks)
            #pragma unroll
            for (int n = 0; n < 2; ++n) {
                const f16x8 b = ldW(wsp + IMG_GW1, n * 16, ks * 32, lane);
                ag[n] = MFMA16(hbA[ks], b, ag[n]);
            }
        const f32x4 gb2v = *(const f32x4*)gb2;
        f32x4 pg[4] = {{0,0,0,0},{0,0,0,0},{0,0,0,0},{0,0,0,0}};
        #pragma unroll
        for (int n = 0; n < 2; ++n) {
            const f32x4 w4 = *(const f32x4*)(gw2 + (n * 16 + c) * 4);
            #pragma unroll
            for (int g = 0; g < 4; ++g)
                pg[g] += silu_f(ag[n][g]) * w4;
        }
        #pragma unroll
        for (int g = 0; g < 4; ++g) {
            f32x4 l = reduce16(pg[g]) + gb2v;
            const float mx = fmaxf(fmaxf(l[0], l[1]), fmaxf(l[2], l[3]));
            f32x4 ee;
            #pragma unroll
            for (int o = 0; o < 4; ++o) ee[o] = __expf(l[o] - mx);
            const f32x4 gv = ee * __builtin_amdgcn_rcpf(ee[0] + ee[1] + ee[2] + ee[3]);
            if (c < 4) {
                const float val = (c == 0) ? gv[0] : (c == 1) ? gv[1] : (c == 2) ? gv[2] : gv[3];
                GWT[wv * 64 + c * 16 + q * 4 + g] = (f16)val;
            }
        }
    }

    // ================= 4 experts (rolled; weights streamed from L2) =================
    f32x4 moe[4] = {{0,0,0,0},{0,0,0,0},{0,0,0,0},{0,0,0,0}};
    #pragma unroll 1
    for (int e = 0; e < 4; ++e) {
        f32x4 a2e[4];
        #pragma unroll
        for (int n = 0; n < 4; ++n) {
            const float bv = eb2[e * 64 + n * 16 + c];
            f32x4 t = {bv, bv, bv, bv};
            a2e[n] = t;
        }
        #pragma unroll
        for (int h = 0; h < 2; ++h) {
            const f16* ebase = wsp + IMG_E + e * 16384 + h * 8192;
            f32x4 aa[4];
            #pragma unroll
            for (int n = 0; n < 4; ++n) {
                const float bv = eb1[e * 128 + h * 64 + n * 16 + c];
                f32x4 t = {bv, bv, bv, bv};
                aa[n] = t;
            }
            mm8(hbA, ebase, aa, lane);            // ew1 colhalf h
            f16x8 ea[2];
            silu_to_frags(STRIP, aa, ea, lane);
            mm8(ea, ebase + 4096, a2e, lane);     // ew2 rowhalf h
        }
        #pragma unroll
        for (int g = 0; g < 4; ++g) {
            const float ge = (float)GWT[wv * 64 + e * 16 + q * 4 + g];
            #pragma unroll
            for (int n = 0; n < 4; ++n)
                moe[n][g] += silu_f(a2e[n][g]) * ge;
        }
    }

    // ================= shared trunk: feat = silu(moe @ sw + sb) =================
    f16x8 featA[2];
    {
        #pragma unroll
        for (int n = 0; n < 4; ++n)
            stS(STRIP, n * 16, moe[n], lane);
        f16x8 ma[2];
        #pragma unroll
        for (int ks = 0; ks < 2; ++ks)
            ma[ks] = ldS(STRIP, ks * 32, lane);
        f32x4 fs[4];
        #pragma unroll
        for (int n = 0; n < 4; ++n) {
            const float bv = sb[n * 16 + c];
            f32x4 t = {bv, bv, bv, bv};
            fs[n] = t;
        }
        mm8(ma, wsp + IMG_SWH, fs, lane);
        silu_to_frags(STRIP, fs, featA, lane);
    }

    // ================= heads =================
    {
        f32x4 ah[6];
        #pragma unroll
        for (int n = 0; n < 6; ++n) {
            const float bv = hb1[(n >> 1) * 32 + (n & 1) * 16 + c];
            f32x4 t = {bv, bv, bv, bv};
            ah[n] = t;
        }
        #pragma unroll
        for (int ks = 0; ks < 2; ++ks)
            #pragma unroll
            for (int n = 0; n < 6; ++n) {
                const int h = n >> 1;
                const f16* hw = (h == 0) ? (wsp + IMG_SWH + 4096)
                              : (h == 1) ? (wsp + IMG_SWH + 6144)
                                         : (wsp + IMG_HW2G);
                const f16x8 b = ldW(hw, (n & 1) * 16, ks * 32, lane);
                ah[n] = MFMA16(featA[ks], b, ah[n]);
            }
        const float hb2_0 = hb2[0], hb2_1 = hb2[1], hb2_2 = hb2[2];
        f32x4 ph[3] = {{0,0,0,0},{0,0,0,0},{0,0,0,0}};
        #pragma unroll
        for (int n = 0; n < 6; ++n) {
            const int h = n >> 1;
            const float w2v = hw2[h * 32 + (n & 1) * 16 + c];
            #pragma unroll
            for (int g = 0; g < 4; ++g)
                ph[h][g] += silu_f(ah[n][g]) * w2v;
        }
        #pragma unroll
        for (int h = 0; h < 3; ++h) ph[h] = reduce16(ph[h]);
        #pragma unroll
        for (int g = 0; g < 4; ++g) {
            const long row = blockRow + wv * 16 + q * 4 + g;
            if (c < 3) {
                const float r0 = ph[0][g] + hb2_0;
                const float r1 = ph[1][g] + hb2_1;
                const float r2 = ph[2][g] + hb2_2;
                out[row * 3 + c] = (c == 0) ? r0 : ((c == 1) ? r1 : r2);
            }
        }
    }
}

extern "C" void kernel_launch(void* const* d_in, const int* in_sizes, int n_in,
                              void* d_out, int out_size, void* d_ws, size_t ws_size,
                              hipStream_t stream) {
    const float* x    = (const float*)d_in[0];
    const float* w1   = (const float*)d_in[1];
    const float* b1   = (const float*)d_in[2];
    const float* lng  = (const float*)d_in[3];
    const float* lnb  = (const float*)d_in[4];
    const float* w2   = (const float*)d_in[5];
    const float* b2   = (const float*)d_in[6];
    const float* ew1  = (const float*)d_in[7];
    const float* eb1  = (const float*)d_in[8];
    const float* ew2  = (const float*)d_in[9];
    const float* eb2  = (const float*)d_in[10];
    const float* gw1  = (const float*)d_in[11];
    const float* gb1  = (const float*)d_in[12];
    const float* gw2  = (const float*)d_in[13];
    const float* gb2  = (const float*)d_in[14];
    const float* sw   = (const float*)d_in[15];
    const float* sb   = (const float*)d_in[16];
    const float* hw1  = (const float*)d_in[17];
    const float* hb1  = (const float*)d_in[18];
    const float* hw2  = (const float*)d_in[19];
    const float* hb2  = (const float*)d_in[20];
    float* out = (float*)d_out;
    f16* ws = (f16*)d_ws;

    hipLaunchKernelGGL(prep_weights, dim3(64), dim3(256), 0, stream,
                       w1, w2, gw1, ew1, ew2, sw, hw1, ws);

    const int B = in_sizes[0] / 256;
    const int grid = B / 64;
    hipLaunchKernelGGL(fused_net_mfma, dim3(grid), dim3(256), 0, stream,
                       x, ws, b1, lng, lnb, b2, eb1, eb2, gb1, gw2, gb2,
                       sb, hb1, hw2, hb2, out);
}

// Round 11
// 142.343 us; speedup vs baseline: 1.3954x; 1.3954x over previous
//
#include <hip/hip_runtime.h>

typedef _Float16 f16;
typedef f16   f16x4 __attribute__((ext_vector_type(4)));
typedef f16   f16x8 __attribute__((ext_vector_type(8)));
typedef float f32x4 __attribute__((ext_vector_type(4)));
typedef __attribute__((address_space(3))) char as3char;

#define MFMA16(a, b, c) __builtin_amdgcn_mfma_f32_16x16x32_f16((a), (b), (c), 0, 0, 0)

// ---- weight images in d_ws (f16 units). granule = [64n][64k^swz] = 4096 f16 = 8KB ----
#define IMG_W1   0        // 4 pairs: pair kq = {granule(kq,n0..63), granule(kq,n64..127)} -> 64KB
#define IMG_W2   32768    // {w2 kh0, w2 kh1} -> 16KB
#define IMG_GW1  40960    // [32n][64k] = 2048 -> 4KB
#define IMG_E    43008    // per e (32KB): h0:{ew1h0,ew2h0} h1:{ew1h1,ew2h1}
#define IMG_SWH  108544   // {sw(4096), hw1[0](2048), hw1[1](2048), hw1[2](2048)} = 20KB contiguous

__device__ __forceinline__ float silu_f(float v) {
    return v * __builtin_amdgcn_rcpf(1.0f + __expf(-v));
}

// ============ prep: fp32 src[K][N] block -> f16 granule [n][k ^ ((n&7)<<3)] ============
__device__ void conv_blk(const float* __restrict__ src, f16* __restrict__ dst,
                         int srcN, int k0, int n0, int KB, int NB, int tid, int nth) {
    for (int i = tid; i < KB * NB; i += nth) {
        const int kk = i / NB, nn = i - kk * NB;
        dst[nn * KB + (kk ^ ((nn & 7) << 3))] = (f16)src[(long)(k0 + kk) * srcN + n0 + nn];
    }
}

__global__ void prep_weights(const float* __restrict__ w1, const float* __restrict__ w2,
                             const float* __restrict__ gw1, const float* __restrict__ ew1,
                             const float* __restrict__ ew2, const float* __restrict__ sw,
                             const float* __restrict__ hw1, f16* __restrict__ ws) {
    const int tid = blockIdx.x * 256 + threadIdx.x;
    const int nth = gridDim.x * 256;
    for (int kq = 0; kq < 4; ++kq)
        for (int nh = 0; nh < 2; ++nh)
            conv_blk(w1, ws + IMG_W1 + (kq * 2 + nh) * 4096, 128, kq * 64, nh * 64, 64, 64, tid, nth);
    for (int kh = 0; kh < 2; ++kh)
        conv_blk(w2, ws + IMG_W2 + kh * 4096, 64, kh * 64, 0, 64, 64, tid, nth);
    conv_blk(gw1, ws + IMG_GW1, 32, 0, 0, 64, 32, tid, nth);
    for (int e = 0; e < 4; ++e)
        for (int h = 0; h < 2; ++h) {
            conv_blk(ew1 + e * 8192, ws + IMG_E + e * 16384 + h * 8192,        128, 0, h * 64, 64, 64, tid, nth);
            conv_blk(ew2 + e * 8192, ws + IMG_E + e * 16384 + h * 8192 + 4096,  64, h * 64, 0, 64, 64, tid, nth);
        }
    conv_blk(sw, ws + IMG_SWH, 64, 0, 0, 64, 64, tid, nth);
    for (int h = 0; h < 3; ++h)
        conv_blk(hw1 + h * 2048, ws + IMG_SWH + 4096 + h * 2048, 32, 0, 0, 64, 32, tid, nth);
}

// ============ async global->LDS staging: 1KB chunks round-robined over 4 waves ============
template<int BYTES>
__device__ __forceinline__ void stage4(const f16* __restrict__ g, as3char* l, int wv, int lane) {
    constexpr int CH = BYTES / 1024;
    #pragma unroll
    for (int ch = 0; ch < CH; ++ch)
        if ((ch & 3) == wv)
            __builtin_amdgcn_global_load_lds(
                (const __attribute__((address_space(1))) void*)((const char*)g + ch * 1024 + lane * 16),
                (__attribute__((address_space(3))) void*)(l + ch * 1024), 16, 0, 0);
}

// ============ swizzles ============
__device__ __forceinline__ int swzW(int n) { return (n & 7) << 3; }
__device__ __forceinline__ int swzS(int r) { return (((((r >> 2) & 3) << 1) | (r & 1))) << 3; }

__device__ __forceinline__ f16x8 ldW(const f16* base, int row_base, int k0, int lane) {
    const int r = row_base + (lane & 15);
    const int k = k0 + ((lane >> 4) << 3);
    return *(const f16x8*)(base + r * 64 + (k ^ swzW(r)));
}
__device__ __forceinline__ f16x8 ldS(const f16* strip, int row_base, int k0, int lane) {
    const int r = row_base + (lane & 15);
    const int k = k0 + ((lane >> 4) << 3);
    return *(const f16x8*)(strip + r * 64 + (k ^ swzS(r)));
}
__device__ __forceinline__ void stS(f16* strip, int row_base, int col_base, f32x4 v, int lane) {
    const int cc = col_base + (lane & 15);
    #pragma unroll
    for (int g = 0; g < 4; ++g) {
        const int r = row_base + ((lane >> 4) << 2) + g;
        strip[r * 64 + (cc ^ swzS(r))] = (f16)v[g];
    }
}

// 16 MFMAs: {c0,c1}[4] += {a0,a1}[2] @ granule (two 16-row M-frags)
__device__ __forceinline__ void mm16(const f16x8 a0[2], const f16x8 a1[2],
                                     const f16* wb, f32x4* c0, f32x4* c1, int lane) {
    #pragma unroll
    for (int ks = 0; ks < 2; ++ks)
        #pragma unroll
        for (int n = 0; n < 4; ++n) {
            const f16x8 b = ldW(wb, n * 16, ks * 32, lane);
            c0[n] = MFMA16(a0[ks], b, c0[n]);
            c1[n] = MFMA16(a1[ks], b, c1[n]);
        }
}

// silu(in) -> strip rows [row_base, row_base+16) -> A-frags
__device__ __forceinline__ void silu_to_frags(f16* strip, int row_base, const f32x4 in[4],
                                              f16x8 outf[2], int lane) {
    #pragma unroll
    for (int n = 0; n < 4; ++n) {
        f32x4 v;
        #pragma unroll
        for (int g = 0; g < 4; ++g) v[g] = silu_f(in[n][g]);
        stS(strip, row_base, n * 16, v, lane);
    }
    #pragma unroll
    for (int ks = 0; ks < 2; ++ks)
        outf[ks] = ldS(strip, row_base, ks * 32, lane);
}

__device__ __forceinline__ f32x4 reduce16(f32x4 v) {
    #pragma unroll
    for (int m = 1; m <= 8; m <<= 1) {
        f32x4 o;
        #pragma unroll
        for (int i = 0; i < 4; ++i) o[i] = __shfl_xor(v[i], m, 64);
        v += o;
    }
    return v;
}

__global__ __launch_bounds__(256, 3)
void fused_net_mfma(const float* __restrict__ x,   const f16* __restrict__ wsp,
                    const float* __restrict__ b1,  const float* __restrict__ lng,
                    const float* __restrict__ lnb, const float* __restrict__ b2,
                    const float* __restrict__ eb1, const float* __restrict__ eb2,
                    const float* __restrict__ gb1, const float* __restrict__ gw2,
                    const float* __restrict__ gb2, const float* __restrict__ sb,
                    const float* __restrict__ hb1, const float* __restrict__ hw2,
                    const float* __restrict__ hb2, float* __restrict__ out)
{
    // 53 KB: strips 4x4KB | WB 32KB | G 4KB | GWT 1KB  -> 3 blocks/CU
    __shared__ __align__(16) f16 lds[27136];
    as3char* const LB = (as3char*)lds;
    const int lane = threadIdx.x & 63;
    const int wv   = threadIdx.x >> 6;
    const int c    = lane & 15;
    const int q    = lane >> 4;
    f16* STRIP = lds + wv * 2048;               // per-wave [32][64]
    f16* const WB  = lds + 8192;   as3char* const WB_3 = LB + 16384;  // 4-granule region
    f16* const G   = lds + 24576;  as3char* const G_3  = LB + 49152;
    f16* const GWT = lds + 26624;               // [wv][e][32 rows] f16

    const long blockRow = (long)blockIdx.x * 128;
    const float* xw = x + (blockRow + wv * 32) * 256;   // this wave's 32 rows

    // ---- P0: stage w1 half0 (kq0,kq1 pairs = 32KB) + gw1 -> G ----
    stage4<32768>(wsp + IMG_W1, WB_3, wv, lane);
    stage4<4096>(wsp + IMG_GW1, G_3, wv, lane);
    __syncthreads();

    // ================= stem1: acc = x @ w1 + b1 (2 fat phases) =================
    f32x4 acc0[8], acc1[8];
    #pragma unroll
    for (int n8 = 0; n8 < 8; ++n8) {
        const float bv = b1[n8 * 16 + c];
        f32x4 t = {bv, bv, bv, bv};
        acc0[n8] = t; acc1[n8] = t;
    }

    #pragma unroll 1
    for (int half = 0; half < 2; ++half) {
        #pragma unroll
        for (int j = 0; j < 2; ++j) {
            const int kq = half * 2 + j;
            // x quarter kq -> strip (transient regs)
            #pragma unroll
            for (int i = 0; i < 8; ++i) {
                const int idx4 = lane + i * 64;
                const int r  = idx4 >> 4;
                const int c4 = (idx4 & 15) << 2;
                const float4 v = *(const float4*)(xw + r * 256 + kq * 64 + c4);
                f16x4 o; o[0] = (f16)v.x; o[1] = (f16)v.y; o[2] = (f16)v.z; o[3] = (f16)v.w;
                *(f16x4*)(STRIP + r * 64 + (c4 ^ swzS(r))) = o;
            }
            f16x8 af0[2], af1[2];
            #pragma unroll
            for (int ks = 0; ks < 2; ++ks) {
                af0[ks] = ldS(STRIP, 0,  ks * 32, lane);
                af1[ks] = ldS(STRIP, 16, ks * 32, lane);
            }
            mm16(af0, af1, WB + (j * 2) * 4096,     acc0,     acc1,     lane);  // nh0
            mm16(af0, af1, WB + (j * 2 + 1) * 4096, acc0 + 4, acc1 + 4, lane);  // nh1
        }
        __syncthreads();
        if (half == 0) stage4<32768>(wsp + IMG_W1 + 16384, WB_3, wv, lane);  // kq2,kq3
        else           stage4<16384>(wsp + IMG_W2,         WB_3, wv, lane);  // w2 pair
        __syncthreads();
    }

    // ---- LN stats (registers only) ----
    f32x4 mu0, rs0, mu1, rs1;
    {
        f32x4 s = {0,0,0,0}, qq = {0,0,0,0};
        #pragma unroll
        for (int n8 = 0; n8 < 8; ++n8) { s += acc0[n8]; qq += acc0[n8] * acc0[n8]; }
        s = reduce16(s); qq = reduce16(qq);
        mu0 = s * 0.0078125f;
        #pragma unroll
        for (int g = 0; g < 4; ++g)
            rs0[g] = rsqrtf(qq[g] * 0.0078125f - mu0[g] * mu0[g] + 1e-5f);
    }
    {
        f32x4 s = {0,0,0,0}, qq = {0,0,0,0};
        #pragma unroll
        for (int n8 = 0; n8 < 8; ++n8) { s += acc1[n8]; qq += acc1[n8] * acc1[n8]; }
        s = reduce16(s); qq = reduce16(qq);
        mu1 = s * 0.0078125f;
        #pragma unroll
        for (int g = 0; g < 4; ++g)
            rs1[g] = rsqrtf(qq[g] * 0.0078125f - mu1[g] * mu1[g] + 1e-5f);
    }

    // ================= stem2 (WB = w2 pair) + gate =================
    f32x4 a20[4], a21[4];
    #pragma unroll
    for (int n = 0; n < 4; ++n) {
        const float bv = b2[n * 16 + c];
        f32x4 t = {bv, bv, bv, bv};
        a20[n] = t; a21[n] = t;
    }
    #pragma unroll
    for (int kh = 0; kh < 2; ++kh) {
        #pragma unroll
        for (int n = 0; n < 4; ++n) {
            const int j = kh * 64 + n * 16 + c;
            const float gg = lng[j], bb = lnb[j];
            f32x4 v0, v1;
            #pragma unroll
            for (int g = 0; g < 4; ++g) {
                v0[g] = silu_f((acc0[kh * 4 + n][g] - mu0[g]) * rs0[g] * gg + bb);
                v1[g] = silu_f((acc1[kh * 4 + n][g] - mu1[g]) * rs1[g] * gg + bb);
            }
            stS(STRIP, 0,  n * 16, v0, lane);
            stS(STRIP, 16, n * 16, v1, lane);
        }
        f16x8 af0[2], af1[2];
        #pragma unroll
        for (int ks = 0; ks < 2; ++ks) {
            af0[ks] = ldS(STRIP, 0,  ks * 32, lane);
            af1[ks] = ldS(STRIP, 16, ks * 32, lane);
        }
        mm16(af0, af1, WB + kh * 4096, a20, a21, lane);
    }
    // hb -> A-frags (16 VGPRs, held through experts)
    f16x8 hbA0[2], hbA1[2];
    silu_to_frags(STRIP, 0,  a20, hbA0, lane);
    silu_to_frags(STRIP, 16, a21, hbA1, lane);

    // ---- gate -> GWT (per-wave LDS) ----
    {
        f32x4 ag0[2], ag1[2];
        #pragma unroll
        for (int n = 0; n < 2; ++n) {
            const float bv = gb1[n * 16 + c];
            f32x4 t = {bv, bv, bv, bv};
            ag0[n] = t; ag1[n] = t;
        }
        #pragma unroll
        for (int ks = 0; ks < 2; ++ks)
            #pragma unroll
            for (int n = 0; n < 2; ++n) {
                const f16x8 b = ldW(G, n * 16, ks * 32, lane);
                ag0[n] = MFMA16(hbA0[ks], b, ag0[n]);
                ag1[n] = MFMA16(hbA1[ks], b, ag1[n]);
            }
        const f32x4 gb2v = *(const f32x4*)gb2;
        #pragma unroll
        for (int m = 0; m < 2; ++m) {
            f32x4 pg[4] = {{0,0,0,0},{0,0,0,0},{0,0,0,0},{0,0,0,0}};
            #pragma unroll
            for (int n = 0; n < 2; ++n) {
                const f32x4 w4 = *(const f32x4*)(gw2 + (n * 16 + c) * 4);
                #pragma unroll
                for (int g = 0; g < 4; ++g)
                    pg[g] += silu_f(m == 0 ? ag0[n][g] : ag1[n][g]) * w4;
            }
            #pragma unroll
            for (int g = 0; g < 4; ++g) {
                f32x4 l = reduce16(pg[g]) + gb2v;
                const float mx = fmaxf(fmaxf(l[0], l[1]), fmaxf(l[2], l[3]));
                f32x4 ee;
                #pragma unroll
                for (int o = 0; o < 4; ++o) ee[o] = __expf(l[o] - mx);
                const f32x4 gv = ee * __builtin_amdgcn_rcpf(ee[0] + ee[1] + ee[2] + ee[3]);
                if (c < 4) {
                    const float val = (c == 0) ? gv[0] : (c == 1) ? gv[1] : (c == 2) ? gv[2] : gv[3];
                    GWT[wv * 128 + c * 32 + m * 16 + q * 4 + g] = (f16)val;
                }
            }
        }
    }
    __syncthreads();
    stage4<32768>(wsp + IMG_E, WB_3, wv, lane);   // expert 0 (whole)
    __syncthreads();

    // ================= 4 experts (rolled; 1 refill per expert) =================
    f32x4 moe0[4] = {{0,0,0,0},{0,0,0,0},{0,0,0,0},{0,0,0,0}};
    f32x4 moe1[4] = {{0,0,0,0},{0,0,0,0},{0,0,0,0},{0,0,0,0}};
    #pragma unroll 1
    for (int e = 0; e < 4; ++e) {
        f32x4 a2e0[4], a2e1[4];
        #pragma unroll
        for (int n = 0; n < 4; ++n) {
            const float bv = eb2[e * 64 + n * 16 + c];
            f32x4 t = {bv, bv, bv, bv};
            a2e0[n] = t; a2e1[n] = t;
        }
        #pragma unroll
        for (int h = 0; h < 2; ++h) {
            const f16* ebase = WB + h * 8192;     // {ew1 colhalf h, ew2 rowhalf h}
            f32x4 aa0[4], aa1[4];
            #pragma unroll
            for (int n = 0; n < 4; ++n) {
                const float bv = eb1[e * 128 + h * 64 + n * 16 + c];
                f32x4 t = {bv, bv, bv, bv};
                aa0[n] = t; aa1[n] = t;
            }
            mm16(hbA0, hbA1, ebase, aa0, aa1, lane);
            f16x8 ea0[2], ea1[2];
            silu_to_frags(STRIP, 0,  aa0, ea0, lane);
            silu_to_frags(STRIP, 16, aa1, ea1, lane);
            mm16(ea0, ea1, ebase + 4096, a2e0, a2e1, lane);
        }
        #pragma unroll
        for (int m = 0; m < 2; ++m)
            #pragma unroll
            for (int g = 0; g < 4; ++g) {
                const float ge = (float)GWT[wv * 128 + e * 32 + m * 16 + q * 4 + g];
                #pragma unroll
                for (int n = 0; n < 4; ++n) {
                    if (m == 0) moe0[n][g] += silu_f(a2e0[n][g]) * ge;
                    else        moe1[n][g] += silu_f(a2e1[n][g]) * ge;
                }
            }
        __syncthreads();
        if (e < 3) stage4<32768>(wsp + IMG_E + (e + 1) * 16384, WB_3, wv, lane);
        else       stage4<20480>(wsp + IMG_SWH, WB_3, wv, lane);   // sw + hw1[0..2]
        __syncthreads();
    }

    // ================= shared trunk: feat = silu(moe @ sw + sb) =================
    f16x8 featA0[2], featA1[2];
    {
        #pragma unroll
        for (int n = 0; n < 4; ++n) {
            stS(STRIP, 0,  n * 16, moe0[n], lane);
            stS(STRIP, 16, n * 16, moe1[n], lane);
        }
        f16x8 ma0[2], ma1[2];
        #pragma unroll
        for (int ks = 0; ks < 2; ++ks) {
            ma0[ks] = ldS(STRIP, 0,  ks * 32, lane);
            ma1[ks] = ldS(STRIP, 16, ks * 32, lane);
        }
        f32x4 fs0[4], fs1[4];
        #pragma unroll
        for (int n = 0; n < 4; ++n) {
            const float bv = sb[n * 16 + c];
            f32x4 t = {bv, bv, bv, bv};
            fs0[n] = t; fs1[n] = t;
        }
        mm16(ma0, ma1, WB, fs0, fs1, lane);
        silu_to_frags(STRIP, 0,  fs0, featA0, lane);
        silu_to_frags(STRIP, 16, fs1, featA1, lane);
    }

    // ================= heads: hw1[h] at WB + 4096 + h*2048 =================
    {
        f32x4 ah0[6], ah1[6];
        #pragma unroll
        for (int n = 0; n < 6; ++n) {
            const float bv = hb1[(n >> 1) * 32 + (n & 1) * 16 + c];
            f32x4 t = {bv, bv, bv, bv};
            ah0[n] = t; ah1[n] = t;
        }
        #pragma unroll
        for (int ks = 0; ks < 2; ++ks)
            #pragma unroll
            for (int n = 0; n < 6; ++n) {
                const f16* hw = WB + 4096 + (n >> 1) * 2048;
                const f16x8 b = ldW(hw, (n & 1) * 16, ks * 32, lane);
                ah0[n] = MFMA16(featA0[ks], b, ah0[n]);
                ah1[n] = MFMA16(featA1[ks], b, ah1[n]);
            }
        const float hb2_0 = hb2[0], hb2_1 = hb2[1], hb2_2 = hb2[2];
        #pragma unroll
        for (int m = 0; m < 2; ++m) {
            f32x4 ph[3] = {{0,0,0,0},{0,0,0,0},{0,0,0,0}};
            #pragma unroll
            for (int n = 0; n < 6; ++n) {
                const int h = n >> 1;
                const float w2v = hw2[h * 32 + (n & 1) * 16 + c];
                #pragma unroll
                for (int g = 0; g < 4; ++g)
                    ph[h][g] += silu_f(m == 0 ? ah0[n][g] : ah1[n][g]) * w2v;
            }
            #pragma unroll
            for (int h = 0; h < 3; ++h) ph[h] = reduce16(ph[h]);
            #pragma unroll
            for (int g = 0; g < 4; ++g) {
                const long row = blockRow + wv * 32 + m * 16 + q * 4 + g;
                if (c < 3) {
                    const float r0 = ph[0][g] + hb2_0;
                    const float r1 = ph[1][g] + hb2_1;
                    const float r2 = ph[2][g] + hb2_2;
                    out[row * 3 + c] = (c == 0) ? r0 : ((c == 1) ? r1 : r2);
                }
            }
        }
    }
}

extern "C" void kernel_launch(void* const* d_in, const int* in_sizes, int n_in,
                              void* d_out, int out_size, void* d_ws, size_t ws_size,
                              hipStream_t stream) {
    const float* x    = (const float*)d_in[0];
    const float* w1   = (const float*)d_in[1];
    const float* b1   = (const float*)d_in[2];
    const float* lng  = (const float*)d_in[3];
    const float* lnb  = (const float*)d_in[4];
    const float* w2   = (const float*)d_in[5];
    const float* b2   = (const float*)d_in[6];
    const float* ew1  = (const float*)d_in[7];
    const float* eb1  = (const float*)d_in[8];
    const float* ew2  = (const float*)d_in[9];
    const float* eb2  = (const float*)d_in[10];
    const float* gw1  = (const float*)d_in[11];
    const float* gb1  = (const float*)d_in[12];
    const float* gw2  = (const float*)d_in[13];
    const float* gb2  = (const float*)d_in[14];
    const float* sw   = (const float*)d_in[15];
    const float* sb   = (const float*)d_in[16];
    const float* hw1  = (const float*)d_in[17];
    const float* hb1  = (const float*)d_in[18];
    const float* hw2  = (const float*)d_in[19];
    const float* hb2  = (const float*)d_in[20];
    float* out = (float*)d_out;
    f16* ws = (f16*)d_ws;

    hipLaunchKernelGGL(prep_weights, dim3(64), dim3(256), 0, stream,
                       w1, w2, gw1, ew1, ew2, sw, hw1, ws);

    const int B = in_sizes[0] / 256;
    const int grid = B / 128;
    hipLaunchKernelGGL(fused_net_mfma, dim3(grid), dim3(256), 0, stream,
                       x, ws, b1, lng, lnb, b2, eb1, eb2, gb1, gw2, gb2,
                       sb, hb1, hw2, hb2, out);
}

// Round 12
// 120.666 us; speedup vs baseline: 1.6461x; 1.1796x over previous
//
#include <hip/hip_runtime.h>

typedef _Float16 f16;
typedef f16   f16x4 __attribute__((ext_vector_type(4)));
typedef f16   f16x8 __attribute__((ext_vector_type(8)));
typedef float f32x4 __attribute__((ext_vector_type(4)));
typedef __attribute__((address_space(3))) char as3char;

#define MFMA16(a, b, c) __builtin_amdgcn_mfma_f32_16x16x32_f16((a), (b), (c), 0, 0, 0)

// ---- weight images in d_ws (f16 units). granule = [64n][64k^swz] = 4096 f16 = 8KB ----
#define IMG_W1   0        // 4 pairs (16KB each): pair kq = {granule(kq,nh0), granule(kq,nh1)}
#define IMG_W2   32768    // {w2 kh0, w2 kh1} = 16KB
#define IMG_GW1  40960    // [32n][64k] = 2048 f16 = 4KB
#define IMG_E    43008    // per e (32KB): half h at +h*8192 = {ew1 colhalf h, ew2 rowhalf h}
#define IMG_SWH  108544   // sw(4096) | hw1[0](2048) | hw1[1](2048) | hw1[2](2048) contiguous

__device__ __forceinline__ float silu_f(float v) {
    return v * __builtin_amdgcn_rcpf(1.0f + __expf(-v));
}

// ============ prep: fp32 src[K][N] block -> f16 granule [n][k ^ ((n&7)<<3)] ============
__device__ void conv_blk(const float* __restrict__ src, f16* __restrict__ dst,
                         int srcN, int k0, int n0, int KB, int NB, int tid, int nth) {
    for (int i = tid; i < KB * NB; i += nth) {
        const int kk = i / NB, nn = i - kk * NB;
        dst[nn * KB + (kk ^ ((nn & 7) << 3))] = (f16)src[(long)(k0 + kk) * srcN + n0 + nn];
    }
}

__global__ void prep_weights(const float* __restrict__ w1, const float* __restrict__ w2,
                             const float* __restrict__ gw1, const float* __restrict__ ew1,
                             const float* __restrict__ ew2, const float* __restrict__ sw,
                             const float* __restrict__ hw1, f16* __restrict__ ws) {
    const int tid = blockIdx.x * 256 + threadIdx.x;
    const int nth = gridDim.x * 256;
    for (int kq = 0; kq < 4; ++kq)
        for (int nh = 0; nh < 2; ++nh)
            conv_blk(w1, ws + IMG_W1 + (kq * 2 + nh) * 4096, 128, kq * 64, nh * 64, 64, 64, tid, nth);
    for (int kh = 0; kh < 2; ++kh)
        conv_blk(w2, ws + IMG_W2 + kh * 4096, 64, kh * 64, 0, 64, 64, tid, nth);
    conv_blk(gw1, ws + IMG_GW1, 32, 0, 0, 64, 32, tid, nth);
    for (int e = 0; e < 4; ++e)
        for (int h = 0; h < 2; ++h) {
            conv_blk(ew1 + e * 8192, ws + IMG_E + e * 16384 + h * 8192,        128, 0, h * 64, 64, 64, tid, nth);
            conv_blk(ew2 + e * 8192, ws + IMG_E + e * 16384 + h * 8192 + 4096,  64, h * 64, 0, 64, 64, tid, nth);
        }
    conv_blk(sw, ws + IMG_SWH, 64, 0, 0, 64, 64, tid, nth);
    for (int h = 0; h < 3; ++h)
        conv_blk(hw1 + h * 2048, ws + IMG_SWH + 4096 + h * 2048, 32, 0, 0, 64, 32, tid, nth);
}

// ============ async global->LDS staging: 1KB chunks round-robined over 4 waves ============
template<int BYTES>
__device__ __forceinline__ void stage4(const f16* __restrict__ g, as3char* l, int wv, int lane) {
    constexpr int CH = BYTES / 1024;
    #pragma unroll
    for (int ch = 0; ch < CH; ++ch)
        if ((ch & 3) == wv)
            __builtin_amdgcn_global_load_lds(
                (const __attribute__((address_space(1))) void*)((const char*)g + ch * 1024 + lane * 16),
                (__attribute__((address_space(3))) void*)(l + ch * 1024), 16, 0, 0);
}

// ============ swizzles ============
__device__ __forceinline__ int swzW(int n) { return (n & 7) << 3; }
__device__ __forceinline__ int swzS(int r) { return (((((r >> 2) & 3) << 1) | (r & 1))) << 3; }

__device__ __forceinline__ f16x8 ldW(const f16* base, int row_base, int k0, int lane) {
    const int r = row_base + (lane & 15);
    const int k = k0 + ((lane >> 4) << 3);
    return *(const f16x8*)(base + r * 64 + (k ^ swzW(r)));
}
__device__ __forceinline__ f16x8 ldS(const f16* strip, int k0, int lane) {
    const int r = lane & 15;
    const int k = k0 + ((lane >> 4) << 3);
    return *(const f16x8*)(strip + r * 64 + (k ^ swzS(r)));
}
__device__ __forceinline__ void stS(f16* strip, int col_base, f32x4 v, int lane) {
    const int cc = col_base + (lane & 15);
    #pragma unroll
    for (int g = 0; g < 4; ++g) {
        const int r = ((lane >> 4) << 2) + g;
        strip[r * 64 + (cc ^ swzS(r))] = (f16)v[g];
    }
}

// 8 MFMAs: acc[4] += A[2] @ granule (M=16 rows)
__device__ __forceinline__ void mm8(const f16x8 a[2], const f16* wb, f32x4 acc[4], int lane) {
    #pragma unroll
    for (int ks = 0; ks < 2; ++ks)
        #pragma unroll
        for (int n = 0; n < 4; ++n) {
            const f16x8 b = ldW(wb, n * 16, ks * 32, lane);
            acc[n] = MFMA16(a[ks], b, acc[n]);
        }
}

// silu(acc) -> strip -> A-frags
__device__ __forceinline__ void silu_to_frags(f16* strip, const f32x4 in[4], f16x8 outf[2], int lane) {
    #pragma unroll
    for (int n = 0; n < 4; ++n) {
        f32x4 v;
        #pragma unroll
        for (int g = 0; g < 4; ++g) v[g] = silu_f(in[n][g]);
        stS(strip, n * 16, v, lane);
    }
    #pragma unroll
    for (int ks = 0; ks < 2; ++ks)
        outf[ks] = ldS(strip, ks * 32, lane);
}

__device__ __forceinline__ f32x4 reduce16(f32x4 v) {
    #pragma unroll
    for (int m = 1; m <= 8; m <<= 1) {
        f32x4 o;
        #pragma unroll
        for (int i = 0; i < 4; ++i) o[i] = __shfl_xor(v[i], m, 64);
        v += o;
    }
    return v;
}

__global__ __launch_bounds__(256, 4)
void fused_net_mfma(const float* __restrict__ x,   const f16* __restrict__ wsp,
                    const float* __restrict__ b1,  const float* __restrict__ lng,
                    const float* __restrict__ lnb, const float* __restrict__ b2,
                    const float* __restrict__ eb1, const float* __restrict__ eb2,
                    const float* __restrict__ gb1, const float* __restrict__ gw2,
                    const float* __restrict__ gb2, const float* __restrict__ sb,
                    const float* __restrict__ hb1, const float* __restrict__ hw2,
                    const float* __restrict__ hb2, float* __restrict__ out)
{
    // 44.5 KB: strips 8K | WA 16K | WB 16K | G 4K | GWT 0.5K  -> 3 blocks/CU
    __shared__ __align__(16) f16 lds[22784];
    as3char* const LB = (as3char*)lds;
    const int lane = threadIdx.x & 63;
    const int wv   = threadIdx.x >> 6;
    const int c    = lane & 15;
    const int q    = lane >> 4;
    f16* STRIP = lds + wv * 1024;                // per-wave [16][64]
    f16* const WA = lds + 4096;   as3char* const WA_3 = LB + 8192;
    f16* const WB = lds + 12288;  as3char* const WB_3 = LB + 24576;
    f16* const G  = lds + 20480;  as3char* const G_3  = LB + 40960;
    f16* const GWT = lds + 22528;                // [wv][e][16 rows] f16

    const long blockRow = (long)blockIdx.x * 64;
    const float* xw = x + (blockRow + wv * 16) * 256;   // this wave's 16 rows

    // ---- prologue: w1 pair0 -> WA, gw1 -> G; x quarter 0 -> regs ----
    stage4<16384>(wsp + IMG_W1, WA_3, wv, lane);
    stage4<4096>(wsp + IMG_GW1, G_3, wv, lane);
    float4 xr[4];
    #pragma unroll
    for (int i = 0; i < 4; ++i) {
        const int idx4 = lane + i * 64;
        xr[i] = *(const float4*)(xw + (idx4 >> 4) * 256 + ((idx4 & 15) << 2));
    }
    __syncthreads();

    // ================= stem1: 4 pipelined phases (stage-early, 1 barrier each) ============
    f32x4 acc[8];
    #pragma unroll
    for (int n8 = 0; n8 < 8; ++n8) {
        const float bv = b1[n8 * 16 + c];
        f32x4 t = {bv, bv, bv, bv};
        acc[n8] = t;
    }

    #pragma unroll
    for (int kq = 0; kq < 4; ++kq) {
        const f16* cur  = (kq & 1) ? WB : WA;
        as3char* nxt3   = (kq & 1) ? WA_3 : WB_3;
        // 1. issue next weight stage (hides under this phase's compute)
        if (kq < 3) stage4<16384>(wsp + IMG_W1 + (kq + 1) * 8192, nxt3, wv, lane);
        else        stage4<16384>(wsp + IMG_W2, nxt3, wv, lane);
        // 2. x quarter -> strip, A-frags
        #pragma unroll
        for (int i = 0; i < 4; ++i) {
            const int idx4 = lane + i * 64;
            const int r  = idx4 >> 4;
            const int c4 = (idx4 & 15) << 2;
            f16x4 o; o[0] = (f16)xr[i].x; o[1] = (f16)xr[i].y; o[2] = (f16)xr[i].z; o[3] = (f16)xr[i].w;
            *(f16x4*)(STRIP + r * 64 + (c4 ^ swzS(r))) = o;
        }
        f16x8 af[2];
        #pragma unroll
        for (int ks = 0; ks < 2; ++ks)
            af[ks] = ldS(STRIP, ks * 32, lane);
        // 3. prefetch next x quarter (16 transient VGPRs)
        if (kq < 3) {
            #pragma unroll
            for (int i = 0; i < 4; ++i) {
                const int idx4 = lane + i * 64;
                xr[i] = *(const float4*)(xw + (idx4 >> 4) * 256 + (kq + 1) * 64 + ((idx4 & 15) << 2));
            }
        }
        // 4. compute (stage + x loads in flight underneath)
        mm8(af, cur,        acc,     lane);
        mm8(af, cur + 4096, acc + 4, lane);
        __syncthreads();   // drains stage(kq+1); next buffer ready
    }

    // ---- LN stats (registers only) ----
    f32x4 mu, rs;
    {
        f32x4 s = {0,0,0,0}, qq = {0,0,0,0};
        #pragma unroll
        for (int n8 = 0; n8 < 8; ++n8) { s += acc[n8]; qq += acc[n8] * acc[n8]; }
        s = reduce16(s); qq = reduce16(qq);
        mu = s * 0.0078125f;
        #pragma unroll
        for (int g = 0; g < 4; ++g)
            rs[g] = rsqrtf(qq[g] * 0.0078125f - mu[g] * mu[g] + 1e-5f);
    }

    // ================= stem2 + gate (cur = WA holds w2 pair; stage e0h0 -> WB) ============
    stage4<16384>(wsp + IMG_E, WB_3, wv, lane);
    f32x4 a2[4];
    #pragma unroll
    for (int n = 0; n < 4; ++n) {
        const float bv = b2[n * 16 + c];
        f32x4 t = {bv, bv, bv, bv};
        a2[n] = t;
    }
    #pragma unroll
    for (int kh = 0; kh < 2; ++kh) {
        #pragma unroll
        for (int n = 0; n < 4; ++n) {
            const int j = kh * 64 + n * 16 + c;
            const float gg = lng[j], bb = lnb[j];
            f32x4 v;
            #pragma unroll
            for (int g = 0; g < 4; ++g)
                v[g] = silu_f((acc[kh * 4 + n][g] - mu[g]) * rs[g] * gg + bb);
            stS(STRIP, n * 16, v, lane);
        }
        f16x8 af[2];
        #pragma unroll
        for (int ks = 0; ks < 2; ++ks)
            af[ks] = ldS(STRIP, ks * 32, lane);
        mm8(af, WA + kh * 4096, a2, lane);
    }
    f16x8 hbA[2];
    silu_to_frags(STRIP, a2, hbA, lane);

    // gate -> GWT (per-wave LDS; wave-ordered, no barrier needed for own reads)
    {
        f32x4 ag[2];
        #pragma unroll
        for (int n = 0; n < 2; ++n) {
            const float bv = gb1[n * 16 + c];
            f32x4 t = {bv, bv, bv, bv};
            ag[n] = t;
        }
        #pragma unroll
        for (int ks = 0; ks < 2; ++ks)
            #pragma unroll
            for (int n = 0; n < 2; ++n) {
                const f16x8 b = ldW(G, n * 16, ks * 32, lane);
                ag[n] = MFMA16(hbA[ks], b, ag[n]);
            }
        const f32x4 gb2v = *(const f32x4*)gb2;
        f32x4 pg[4] = {{0,0,0,0},{0,0,0,0},{0,0,0,0},{0,0,0,0}};
        #pragma unroll
        for (int n = 0; n < 2; ++n) {
            const f32x4 w4 = *(const f32x4*)(gw2 + (n * 16 + c) * 4);
            #pragma unroll
            for (int g = 0; g < 4; ++g)
                pg[g] += silu_f(ag[n][g]) * w4;
        }
        #pragma unroll
        for (int g = 0; g < 4; ++g) {
            f32x4 l = reduce16(pg[g]) + gb2v;
            const float mx = fmaxf(fmaxf(l[0], l[1]), fmaxf(l[2], l[3]));
            f32x4 ee;
            #pragma unroll
            for (int o = 0; o < 4; ++o) ee[o] = __expf(l[o] - mx);
            const f32x4 gv = ee * __builtin_amdgcn_rcpf(ee[0] + ee[1] + ee[2] + ee[3]);
            if (c < 4) {
                const float val = (c == 0) ? gv[0] : (c == 1) ? gv[1] : (c == 2) ? gv[2] : gv[3];
                GWT[wv * 64 + c * 16 + q * 4 + g] = (f16)val;
            }
        }
    }
    __syncthreads();   // e0h0 ready in WB

    // ================= 4 experts: 2 pipelined phases each (h0 from WB, h1 from WA) ========
    f32x4 moe[4] = {{0,0,0,0},{0,0,0,0},{0,0,0,0},{0,0,0,0}};
    #pragma unroll 1
    for (int e = 0; e < 4; ++e) {
        f32x4 a2e[4];
        #pragma unroll
        for (int n = 0; n < 4; ++n) {
            const float bv = eb2[e * 64 + n * 16 + c];
            f32x4 t = {bv, bv, bv, bv};
            a2e[n] = t;
        }
        // ---- h = 0 (cur = WB): stage (e)h1 -> WA ----
        stage4<16384>(wsp + IMG_E + e * 16384 + 8192, WA_3, wv, lane);
        {
            f32x4 aa[4];
            #pragma unroll
            for (int n = 0; n < 4; ++n) {
                const float bv = eb1[e * 128 + n * 16 + c];
                f32x4 t = {bv, bv, bv, bv};
                aa[n] = t;
            }
            mm8(hbA, WB, aa, lane);
            f16x8 ea[2];
            silu_to_frags(STRIP, aa, ea, lane);
            mm8(ea, WB + 4096, a2e, lane);
        }
        __syncthreads();
        // ---- h = 1 (cur = WA): stage (e+1)h0 -> WB (or sw+hw1[0]) ----
        if (e < 3) stage4<16384>(wsp + IMG_E + (e + 1) * 16384, WB_3, wv, lane);
        else       stage4<12288>(wsp + IMG_SWH, WB_3, wv, lane);
        {
            f32x4 aa[4];
            #pragma unroll
            for (int n = 0; n < 4; ++n) {
                const float bv = eb1[e * 128 + 64 + n * 16 + c];
                f32x4 t = {bv, bv, bv, bv};
                aa[n] = t;
            }
            mm8(hbA, WA, aa, lane);
            f16x8 ea[2];
            silu_to_frags(STRIP, aa, ea, lane);
            mm8(ea, WA + 4096, a2e, lane);
        }
        #pragma unroll
        for (int g = 0; g < 4; ++g) {
            const float ge = (float)GWT[wv * 64 + e * 16 + q * 4 + g];
            #pragma unroll
            for (int n = 0; n < 4; ++n)
                moe[n][g] += silu_f(a2e[n][g]) * ge;
        }
        __syncthreads();
    }

    // ================= feat (cur = WB: sw@0, hw1[0]@4096); stage hw1[1,2] -> WA ===========
    stage4<8192>(wsp + IMG_SWH + 6144, WA_3, wv, lane);
    f16x8 featA[2];
    {
        #pragma unroll
        for (int n = 0; n < 4; ++n)
            stS(STRIP, n * 16, moe[n], lane);
        f16x8 ma[2];
        #pragma unroll
        for (int ks = 0; ks < 2; ++ks)
            ma[ks] = ldS(STRIP, ks * 32, lane);
        f32x4 fs[4];
        #pragma unroll
        for (int n = 0; n < 4; ++n) {
            const float bv = sb[n * 16 + c];
            f32x4 t = {bv, bv, bv, bv};
            fs[n] = t;
        }
        mm8(ma, WB, fs, lane);
        silu_to_frags(STRIP, fs, featA, lane);
    }
    __syncthreads();   // hw1[1,2] ready in WA

    // ================= heads: hw1[0]=WB+4096, hw1[1]=WA+0, hw1[2]=WA+2048 =================
    {
        f32x4 ah[6];
        #pragma unroll
        for (int n = 0; n < 6; ++n) {
            const float bv = hb1[(n >> 1) * 32 + (n & 1) * 16 + c];
            f32x4 t = {bv, bv, bv, bv};
            ah[n] = t;
        }
        #pragma unroll
        for (int ks = 0; ks < 2; ++ks)
            #pragma unroll
            for (int n = 0; n < 6; ++n) {
                const int h = n >> 1;
                const f16* hw = (h == 0) ? (WB + 4096) : (h == 1) ? WA : (WA + 2048);
                const f16x8 b = ldW(hw, (n & 1) * 16, ks * 32, lane);
                ah[n] = MFMA16(featA[ks], b, ah[n]);
            }
        const float hb2_0 = hb2[0], hb2_1 = hb2[1], hb2_2 = hb2[2];
        f32x4 ph[3] = {{0,0,0,0},{0,0,0,0},{0,0,0,0}};
        #pragma unroll
        for (int n = 0; n < 6; ++n) {
            const int h = n >> 1;
            const float w2v = hw2[h * 32 + (n & 1) * 16 + c];
            #pragma unroll
            for (int g = 0; g < 4; ++g)
                ph[h][g] += silu_f(ah[n][g]) * w2v;
        }
        #pragma unroll
        for (int h = 0; h < 3; ++h) ph[h] = reduce16(ph[h]);
        #pragma unroll
        for (int g = 0; g < 4; ++g) {
            const long row = blockRow + wv * 16 + q * 4 + g;
            if (c < 3) {
                const float r0 = ph[0][g] + hb2_0;
                const float r1 = ph[1][g] + hb2_1;
                const float r2 = ph[2][g] + hb2_2;
                out[row * 3 + c] = (c == 0) ? r0 : ((c == 1) ? r1 : r2);
            }
        }
    }
}

extern "C" void kernel_launch(void* const* d_in, const int* in_sizes, int n_in,
                              void* d_out, int out_size, void* d_ws, size_t ws_size,
                              hipStream_t stream) {
    const float* x    = (const float*)d_in[0];
    const float* w1   = (const float*)d_in[1];
    const float* b1   = (const float*)d_in[2];
    const float* lng  = (const float*)d_in[3];
    const float* lnb  = (const float*)d_in[4];
    const float* w2   = (const float*)d_in[5];
    const float* b2   = (const float*)d_in[6];
    const float* ew1  = (const float*)d_in[7];
    const float* eb1  = (const float*)d_in[8];
    const float* ew2  = (const float*)d_in[9];
    const float* eb2  = (const float*)d_in[10];
    const float* gw1  = (const float*)d_in[11];
    const float* gb1  = (const float*)d_in[12];
    const float* gw2  = (const float*)d_in[13];
    const float* gb2  = (const float*)d_in[14];
    const float* sw   = (const float*)d_in[15];
    const float* sb   = (const float*)d_in[16];
    const float* hw1  = (const float*)d_in[17];
    const float* hb1  = (const float*)d_in[18];
    const float* hw2  = (const float*)d_in[19];
    const float* hb2  = (const float*)d_in[20];
    float* out = (float*)d_out;
    f16* ws = (f16*)d_ws;

    hipLaunchKernelGGL(prep_weights, dim3(64), dim3(256), 0, stream,
                       w1, w2, gw1, ew1, ew2, sw, hw1, ws);

    const int B = in_sizes[0] / 256;
    const int grid = B / 64;
    hipLaunchKernelGGL(fused_net_mfma, dim3(grid), dim3(256), 0, stream,
                       x, ws, b1, lng, lnb, b2, eb1, eb2, gb1, gw2, gb2,
                       sb, hb1, hw2, hb2, out);
}

// Round 13
// 102.329 us; speedup vs baseline: 1.9410x; 1.1792x over previous
//
#include <hip/hip_runtime.h>

typedef _Float16 f16;
typedef f16   f16x4 __attribute__((ext_vector_type(4)));
typedef f16   f16x8 __attribute__((ext_vector_type(8)));
typedef float f32x4 __attribute__((ext_vector_type(4)));
typedef __attribute__((address_space(3))) char as3char;

#define MFMA16(a, b, c) __builtin_amdgcn_mfma_f32_16x16x32_f16((a), (b), (c), 0, 0, 0)

// ---- weight images in d_ws (f16 units). granule = [64n][64k^swz] = 4096 f16 = 8KB ----
#define IMG_W1   0        // 8 granules: (kq*2+nh)
#define IMG_W2   32768    // {w2 kh0, w2 kh1}
#define IMG_GW1  40960    // [32n][64k] = 2048 f16
#define IMG_E    43008    // per e (16384): h*8192 + {ew1 colhalf h @0, ew2 rowhalf h @4096}
#define IMG_SWH  108544   // sw(4096) | hw1[0](2048) | hw1[1](2048) | hw1[2](2048)

__device__ __forceinline__ float silu_f(float v) {
    return v * __builtin_amdgcn_rcpf(1.0f + __expf(-v));
}

// ============ prep: fp32 src[K][N] block -> f16 granule [n][k ^ ((n&7)<<3)] ============
__device__ void conv_blk(const float* __restrict__ src, f16* __restrict__ dst,
                         int srcN, int k0, int n0, int KB, int NB, int tid, int nth) {
    for (int i = tid; i < KB * NB; i += nth) {
        const int kk = i / NB, nn = i - kk * NB;
        dst[nn * KB + (kk ^ ((nn & 7) << 3))] = (f16)src[(long)(k0 + kk) * srcN + n0 + nn];
    }
}

__global__ void prep_weights(const float* __restrict__ w1, const float* __restrict__ w2,
                             const float* __restrict__ gw1, const float* __restrict__ ew1,
                             const float* __restrict__ ew2, const float* __restrict__ sw,
                             const float* __restrict__ hw1, f16* __restrict__ ws) {
    const int tid = blockIdx.x * 256 + threadIdx.x;
    const int nth = gridDim.x * 256;
    for (int kq = 0; kq < 4; ++kq)
        for (int nh = 0; nh < 2; ++nh)
            conv_blk(w1, ws + IMG_W1 + (kq * 2 + nh) * 4096, 128, kq * 64, nh * 64, 64, 64, tid, nth);
    for (int kh = 0; kh < 2; ++kh)
        conv_blk(w2, ws + IMG_W2 + kh * 4096, 64, kh * 64, 0, 64, 64, tid, nth);
    conv_blk(gw1, ws + IMG_GW1, 32, 0, 0, 64, 32, tid, nth);
    for (int e = 0; e < 4; ++e)
        for (int h = 0; h < 2; ++h) {
            conv_blk(ew1 + e * 8192, ws + IMG_E + e * 16384 + h * 8192,        128, 0, h * 64, 64, 64, tid, nth);
            conv_blk(ew2 + e * 8192, ws + IMG_E + e * 16384 + h * 8192 + 4096,  64, h * 64, 0, 64, 64, tid, nth);
        }
    conv_blk(sw, ws + IMG_SWH, 64, 0, 0, 64, 64, tid, nth);
    for (int h = 0; h < 3; ++h)
        conv_blk(hw1 + h * 2048, ws + IMG_SWH + 4096 + h * 2048, 32, 0, 0, 64, 32, tid, nth);
}

// ============ async global->LDS staging: 1KB chunks round-robined over 4 waves ============
template<int BYTES>
__device__ __forceinline__ void stage4(const f16* __restrict__ g, as3char* l, int wv, int lane) {
    constexpr int CH = BYTES / 1024;
    #pragma unroll
    for (int ch = 0; ch < CH; ++ch)
        if ((ch & 3) == wv)
            __builtin_amdgcn_global_load_lds(
                (const __attribute__((address_space(1))) void*)((const char*)g + ch * 1024 + lane * 16),
                (__attribute__((address_space(3))) void*)(l + ch * 1024), 16, 0, 0);
}

// ============ swizzles ============
__device__ __forceinline__ int swzW(int n) { return (n & 7) << 3; }
__device__ __forceinline__ int swzS(int r) { return (((((r >> 2) & 3) << 1) | (r & 1))) << 3; }

__device__ __forceinline__ f16x8 ldW(const f16* base, int row_base, int k0, int lane) {
    const int r = row_base + (lane & 15);
    const int k = k0 + ((lane >> 4) << 3);
    return *(const f16x8*)(base + r * 64 + (k ^ swzW(r)));
}
__device__ __forceinline__ f16x8 ldS(const f16* strip, int k0, int lane) {
    const int r = lane & 15;
    const int k = k0 + ((lane >> 4) << 3);
    return *(const f16x8*)(strip + r * 64 + (k ^ swzS(r)));
}
__device__ __forceinline__ void stS(f16* strip, int col_base, f32x4 v, int lane) {
    const int cc = col_base + (lane & 15);
    #pragma unroll
    for (int g = 0; g < 4; ++g) {
        const int r = ((lane >> 4) << 2) + g;
        strip[r * 64 + (cc ^ swzS(r))] = (f16)v[g];
    }
}

// 8 MFMAs: acc[4] += A[2] @ granule (M=16 rows)
__device__ __forceinline__ void mm8(const f16x8 a[2], const f16* wb, f32x4 acc[4], int lane) {
    #pragma unroll
    for (int ks = 0; ks < 2; ++ks)
        #pragma unroll
        for (int n = 0; n < 4; ++n) {
            const f16x8 b = ldW(wb, n * 16, ks * 32, lane);
            acc[n] = MFMA16(a[ks], b, acc[n]);
        }
}

// silu(acc) -> strip -> A-frags
__device__ __forceinline__ void silu_to_frags(f16* strip, const f32x4 in[4], f16x8 outf[2], int lane) {
    #pragma unroll
    for (int n = 0; n < 4; ++n) {
        f32x4 v;
        #pragma unroll
        for (int g = 0; g < 4; ++g) v[g] = silu_f(in[n][g]);
        stS(strip, n * 16, v, lane);
    }
    #pragma unroll
    for (int ks = 0; ks < 2; ++ks)
        outf[ks] = ldS(strip, ks * 32, lane);
}

__device__ __forceinline__ f32x4 reduce16(f32x4 v) {
    #pragma unroll
    for (int m = 1; m <= 8; m <<= 1) {
        f32x4 o;
        #pragma unroll
        for (int i = 0; i < 4; ++i) o[i] = __shfl_xor(v[i], m, 64);
        v += o;
    }
    return v;
}

__global__ __launch_bounds__(256, 4)
void fused_net_mfma(const float* __restrict__ x,   const f16* __restrict__ wsp,
                    const float* __restrict__ b1,  const float* __restrict__ lng,
                    const float* __restrict__ lnb, const float* __restrict__ b2,
                    const float* __restrict__ eb1, const float* __restrict__ eb2,
                    const float* __restrict__ gb1, const float* __restrict__ gw2,
                    const float* __restrict__ gb2, const float* __restrict__ sb,
                    const float* __restrict__ hb1, const float* __restrict__ hw2,
                    const float* __restrict__ hb2, float* __restrict__ out)
{
    // 29184 B: strips 4x2KB | WA 8KB | WB 8KB | G 4KB | GWT 0.5KB  -> 5 blocks/CU
    __shared__ __align__(16) f16 lds[14592];
    as3char* const LB = (as3char*)lds;
    const int lane = threadIdx.x & 63;
    const int wv   = threadIdx.x >> 6;
    const int c    = lane & 15;
    const int q    = lane >> 4;
    f16* STRIP = lds + wv * 1024;                // per-wave [16][64]
    f16* const WA = lds + 4096;   as3char* const WA_3 = LB + 8192;
    f16* const WB = lds + 8192;   as3char* const WB_3 = LB + 16384;
    f16* const G  = lds + 12288;  as3char* const G_3  = LB + 24576;
    f16* const GWT = lds + 14336;                // [wv][e][16 rows] f16

    const long blockRow = (long)blockIdx.x * 64;
    const float* xw = x + (blockRow + wv * 16) * 256;   // this wave's 16 rows

    // ---- prologue: granule0 (w1 kq0,nh0) -> WA, gw1 -> G; x quarter 0 -> regs ----
    stage4<8192>(wsp + IMG_W1, WA_3, wv, lane);
    stage4<4096>(wsp + IMG_GW1, G_3, wv, lane);
    float4 xr[4];
    #pragma unroll
    for (int i = 0; i < 4; ++i) {
        const int idx4 = lane + i * 64;
        xr[i] = *(const float4*)(xw + (idx4 >> 4) * 256 + ((idx4 & 15) << 2));
    }
    __syncthreads();

    // ================= stem1: 8 pipelined granule phases =================
    f32x4 acc[8];
    #pragma unroll
    for (int n8 = 0; n8 < 8; ++n8) {
        const float bv = b1[n8 * 16 + c];
        f32x4 t = {bv, bv, bv, bv};
        acc[n8] = t;
    }

    #pragma unroll 1
    for (int kq = 0; kq < 4; ++kq) {
        const f16* curA = (kq & 1) ? WB : WA;          // phase 2kq parity
        as3char* othA   = (kq & 1) ? WA_3 : WB_3;
        const f16* curB = (kq & 1) ? WA : WB;          // phase 2kq+1 parity
        as3char* othB   = (kq & 1) ? WB_3 : WA_3;

        // ---- phase 2kq (cur: w1(kq,nh0)): stage w1(kq,nh1) -> other ----
        stage4<8192>(wsp + IMG_W1 + (kq * 2 + 1) * 4096, othA, wv, lane);
        #pragma unroll
        for (int i = 0; i < 4; ++i) {
            const int idx4 = lane + i * 64;
            const int r  = idx4 >> 4;
            const int c4 = (idx4 & 15) << 2;
            f16x4 o; o[0] = (f16)xr[i].x; o[1] = (f16)xr[i].y; o[2] = (f16)xr[i].z; o[3] = (f16)xr[i].w;
            *(f16x4*)(STRIP + r * 64 + (c4 ^ swzS(r))) = o;
        }
        f16x8 af[2];
        #pragma unroll
        for (int ks = 0; ks < 2; ++ks)
            af[ks] = ldS(STRIP, ks * 32, lane);
        mm8(af, curA, acc, lane);
        __syncthreads();

        // ---- phase 2kq+1 (cur: w1(kq,nh1)): stage next w1(kq+1,nh0) or w2kh0 ----
        if (kq < 3) stage4<8192>(wsp + IMG_W1 + (kq + 1) * 2 * 4096, othB, wv, lane);
        else        stage4<8192>(wsp + IMG_W2, othB, wv, lane);
        if (kq < 3) {
            #pragma unroll
            for (int i = 0; i < 4; ++i) {
                const int idx4 = lane + i * 64;
                xr[i] = *(const float4*)(xw + (idx4 >> 4) * 256 + (kq + 1) * 64 + ((idx4 & 15) << 2));
            }
        }
        mm8(af, curB, acc + 4, lane);
        __syncthreads();
    }

    // ---- LN stats (registers only) ----
    f32x4 mu, rs;
    {
        f32x4 s = {0,0,0,0}, qq = {0,0,0,0};
        #pragma unroll
        for (int n8 = 0; n8 < 8; ++n8) { s += acc[n8]; qq += acc[n8] * acc[n8]; }
        s = reduce16(s); qq = reduce16(qq);
        mu = s * 0.0078125f;
        #pragma unroll
        for (int g = 0; g < 4; ++g)
            rs[g] = rsqrtf(qq[g] * 0.0078125f - mu[g] * mu[g] + 1e-5f);
    }

    // ================= phase 8 (WA: w2 kh0): stage w2kh1 -> WB =================
    f32x4 a2[4];
    #pragma unroll
    for (int n = 0; n < 4; ++n) {
        const float bv = b2[n * 16 + c];
        f32x4 t = {bv, bv, bv, bv};
        a2[n] = t;
    }
    stage4<8192>(wsp + IMG_W2 + 4096, WB_3, wv, lane);
    {
        #pragma unroll
        for (int n = 0; n < 4; ++n) {
            const int j = n * 16 + c;
            const float gg = lng[j], bb = lnb[j];
            f32x4 v;
            #pragma unroll
            for (int g = 0; g < 4; ++g)
                v[g] = silu_f((acc[n][g] - mu[g]) * rs[g] * gg + bb);
            stS(STRIP, n * 16, v, lane);
        }
        f16x8 af[2];
        #pragma unroll
        for (int ks = 0; ks < 2; ++ks)
            af[ks] = ldS(STRIP, ks * 32, lane);
        mm8(af, WA, a2, lane);
    }
    __syncthreads();

    // ================= phase 9 (WB: w2 kh1): stage e0 ew1h0 -> WA; gate ===========
    stage4<8192>(wsp + IMG_E, WA_3, wv, lane);
    f16x8 hbA[2];
    {
        #pragma unroll
        for (int n = 0; n < 4; ++n) {
            const int j = 64 + n * 16 + c;
            const float gg = lng[j], bb = lnb[j];
            f32x4 v;
            #pragma unroll
            for (int g = 0; g < 4; ++g)
                v[g] = silu_f((acc[4 + n][g] - mu[g]) * rs[g] * gg + bb);
            stS(STRIP, n * 16, v, lane);
        }
        f16x8 af[2];
        #pragma unroll
        for (int ks = 0; ks < 2; ++ks)
            af[ks] = ldS(STRIP, ks * 32, lane);
        mm8(af, WB, a2, lane);
        silu_to_frags(STRIP, a2, hbA, lane);

        // gate (uses G = gw1) -> GWT
        f32x4 ag[2];
        #pragma unroll
        for (int n = 0; n < 2; ++n) {
            const float bv = gb1[n * 16 + c];
            f32x4 t = {bv, bv, bv, bv};
            ag[n] = t;
        }
        #pragma unroll
        for (int ks = 0; ks < 2; ++ks)
            #pragma unroll
            for (int n = 0; n < 2; ++n) {
                const f16x8 b = ldW(G, n * 16, ks * 32, lane);
                ag[n] = MFMA16(hbA[ks], b, ag[n]);
            }
        const f32x4 gb2v = *(const f32x4*)gb2;
        f32x4 pg[4] = {{0,0,0,0},{0,0,0,0},{0,0,0,0},{0,0,0,0}};
        #pragma unroll
        for (int n = 0; n < 2; ++n) {
            const f32x4 w4 = *(const f32x4*)(gw2 + (n * 16 + c) * 4);
            #pragma unroll
            for (int g = 0; g < 4; ++g)
                pg[g] += silu_f(ag[n][g]) * w4;
        }
        #pragma unroll
        for (int g = 0; g < 4; ++g) {
            f32x4 l = reduce16(pg[g]) + gb2v;
            const float mx = fmaxf(fmaxf(l[0], l[1]), fmaxf(l[2], l[3]));
            f32x4 ee;
            #pragma unroll
            for (int o = 0; o < 4; ++o) ee[o] = __expf(l[o] - mx);
            const f32x4 gv = ee * __builtin_amdgcn_rcpf(ee[0] + ee[1] + ee[2] + ee[3]);
            if (c < 4) {
                const float val = (c == 0) ? gv[0] : (c == 1) ? gv[1] : (c == 2) ? gv[2] : gv[3];
                GWT[wv * 64 + c * 16 + q * 4 + g] = (f16)val;
            }
        }
    }
    __syncthreads();   // e0 ew1h0 ready in WA

    // ================= 4 experts: 4 pipelined phases each (WA,WB,WA,WB) =================
    f32x4 moe[4] = {{0,0,0,0},{0,0,0,0},{0,0,0,0},{0,0,0,0}};
    #pragma unroll 1
    for (int e = 0; e < 4; ++e) {
        const f16* ebase = wsp + IMG_E + e * 16384;
        f32x4 a2e[4];
        #pragma unroll
        for (int n = 0; n < 4; ++n) {
            const float bv = eb2[e * 64 + n * 16 + c];
            f32x4 t = {bv, bv, bv, bv};
            a2e[n] = t;
        }
        f16x8 ea[2];
        // --- phase A (WA: ew1 h0): stage ew2h0 -> WB ---
        stage4<8192>(ebase + 4096, WB_3, wv, lane);
        {
            f32x4 aa[4];
            #pragma unroll
            for (int n = 0; n < 4; ++n) {
                const float bv = eb1[e * 128 + n * 16 + c];
                f32x4 t = {bv, bv, bv, bv};
                aa[n] = t;
            }
            mm8(hbA, WA, aa, lane);
            silu_to_frags(STRIP, aa, ea, lane);
        }
        __syncthreads();
        // --- phase B (WB: ew2 h0): stage ew1h1 -> WA ---
        stage4<8192>(ebase + 8192, WA_3, wv, lane);
        mm8(ea, WB, a2e, lane);
        __syncthreads();
        // --- phase C (WA: ew1 h1): stage ew2h1 -> WB ---
        stage4<8192>(ebase + 8192 + 4096, WB_3, wv, lane);
        {
            f32x4 aa[4];
            #pragma unroll
            for (int n = 0; n < 4; ++n) {
                const float bv = eb1[e * 128 + 64 + n * 16 + c];
                f32x4 t = {bv, bv, bv, bv};
                aa[n] = t;
            }
            mm8(hbA, WA, aa, lane);
            silu_to_frags(STRIP, aa, ea, lane);
        }
        __syncthreads();
        // --- phase D (WB: ew2 h1): stage next ew1h0 (or sw) -> WA ---
        if (e < 3) stage4<8192>(wsp + IMG_E + (e + 1) * 16384, WA_3, wv, lane);
        else       stage4<8192>(wsp + IMG_SWH, WA_3, wv, lane);
        mm8(ea, WB, a2e, lane);
        #pragma unroll
        for (int g = 0; g < 4; ++g) {
            const float ge = (float)GWT[wv * 64 + e * 16 + q * 4 + g];
            #pragma unroll
            for (int n = 0; n < 4; ++n)
                moe[n][g] += silu_f(a2e[n][g]) * ge;
        }
        __syncthreads();
    }

    // ================= phase 26 (WA: sw): stage hw1[0,1] -> WB, hw1[2] -> G ============
    stage4<8192>(wsp + IMG_SWH + 4096, WB_3, wv, lane);
    stage4<4096>(wsp + IMG_SWH + 8192, G_3, wv, lane);
    f16x8 featA[2];
    {
        #pragma unroll
        for (int n = 0; n < 4; ++n)
            stS(STRIP, n * 16, moe[n], lane);
        f16x8 ma[2];
        #pragma unroll
        for (int ks = 0; ks < 2; ++ks)
            ma[ks] = ldS(STRIP, ks * 32, lane);
        f32x4 fs[4];
        #pragma unroll
        for (int n = 0; n < 4; ++n) {
            const float bv = sb[n * 16 + c];
            f32x4 t = {bv, bv, bv, bv};
            fs[n] = t;
        }
        mm8(ma, WA, fs, lane);
        silu_to_frags(STRIP, fs, featA, lane);
    }
    __syncthreads();   // hw1[0,1] in WB, hw1[2] in G

    // ================= phase 27: heads (WB: hw1[0]@0, hw1[1]@2048; G: hw1[2]) ==========
    {
        f32x4 ah[6];
        #pragma unroll
        for (int n = 0; n < 6; ++n) {
            const float bv = hb1[(n >> 1) * 32 + (n & 1) * 16 + c];
            f32x4 t = {bv, bv, bv, bv};
            ah[n] = t;
        }
        #pragma unroll
        for (int ks = 0; ks < 2; ++ks)
            #pragma unroll
            for (int n = 0; n < 6; ++n) {
                const int h = n >> 1;
                const f16* hw = (h == 0) ? WB : (h == 1) ? (WB + 2048) : G;
                const f16x8 b = ldW(hw, (n & 1) * 16, ks * 32, lane);
                ah[n] = MFMA16(featA[ks], b, ah[n]);
            }
        const float hb2_0 = hb2[0], hb2_1 = hb2[1], hb2_2 = hb2[2];
        f32x4 ph[3] = {{0,0,0,0},{0,0,0,0},{0,0,0,0}};
        #pragma unroll
        for (int n = 0; n < 6; ++n) {
            const int h = n >> 1;
            const float w2v = hw2[h * 32 + (n & 1) * 16 + c];
            #pragma unroll
            for (int g = 0; g < 4; ++g)
                ph[h][g] += silu_f(ah[n][g]) * w2v;
        }
        #pragma unroll
        for (int h = 0; h < 3; ++h) ph[h] = reduce16(ph[h]);
        #pragma unroll
        for (int g = 0; g < 4; ++g) {
            const long row = blockRow + wv * 16 + q * 4 + g;
            if (c < 3) {
                const float r0 = ph[0][g] + hb2_0;
                const float r1 = ph[1][g] + hb2_1;
                const float r2 = ph[2][g] + hb2_2;
                out[row * 3 + c] = (c == 0) ? r0 : ((c == 1) ? r1 : r2);
            }
        }
    }
}

extern "C" void kernel_launch(void* const* d_in, const int* in_sizes, int n_in,
                              void* d_out, int out_size, void* d_ws, size_t ws_size,
                              hipStream_t stream) {
    const float* x    = (const float*)d_in[0];
    const float* w1   = (const float*)d_in[1];
    const float* b1   = (const float*)d_in[2];
    const float* lng  = (const float*)d_in[3];
    const float* lnb  = (const float*)d_in[4];
    const float* w2   = (const float*)d_in[5];
    const float* b2   = (const float*)d_in[6];
    const float* ew1  = (const float*)d_in[7];
    const float* eb1  = (const float*)d_in[8];
    const float* ew2  = (const float*)d_in[9];
    const float* eb2  = (const float*)d_in[10];
    const float* gw1  = (const float*)d_in[11];
    const float* gb1  = (const float*)d_in[12];
    const float* gw2  = (const float*)d_in[13];
    const float* gb2  = (const float*)d_in[14];
    const float* sw   = (const float*)d_in[15];
    const float* sb   = (const float*)d_in[16];
    const float* hw1  = (const float*)d_in[17];
    const float* hb1  = (const float*)d_in[18];
    const float* hw2  = (const float*)d_in[19];
    const float* hb2  = (const float*)d_in[20];
    float* out = (float*)d_out;
    f16* ws = (f16*)d_ws;

    hipLaunchKernelGGL(prep_weights, dim3(64), dim3(256), 0, stream,
                       w1, w2, gw1, ew1, ew2, sw, hw1, ws);

    const int B = in_sizes[0] / 256;
    const int grid = B / 64;
    hipLaunchKernelGGL(fused_net_mfma, dim3(grid), dim3(256), 0, stream,
                       x, ws, b1, lng, lnb, b2, eb1, eb2, gb1, gw2, gb2,
                       sb, hb1, hw2, hb2, out);
}

// Round 14
// 100.773 us; speedup vs baseline: 1.9710x; 1.0154x over previous
//
#include <hip/hip_runtime.h>

typedef _Float16 f16;
typedef f16   f16x8 __attribute__((ext_vector_type(8)));
typedef float f32x4 __attribute__((ext_vector_type(4)));
typedef __attribute__((address_space(3))) char as3char;

#define MFMA16(a, b, c) __builtin_amdgcn_mfma_f32_16x16x32_f16((a), (b), (c), 0, 0, 0)

// ---- weight images in d_ws (f16 units). granule = [64n][64k^swz] = 4096 f16 = 8KB ----
// All granules except w1 have k-rows pre-permuted by sigma (matches in-register
// B-frag packing of the previous layer's D output). w1 keeps natural k (x loaded raw).
#define IMG_W1   0        // 8 granules: (kq*2+nh), natural k
#define IMG_W2   32768    // {w2 kh0, w2 kh1}, sigma k within each 64-half
#define IMG_GW1  40960    // [32n][64k sigma]
#define IMG_E    43008    // per e (16384): h*8192 + {ew1 colhalf h @0, ew2 rowhalf h @4096}, sigma
#define IMG_SWH  108544   // sw(4096) | hw1[0](2048) | hw1[1](2048) | hw1[2](2048), sigma

__device__ __forceinline__ float silu_f(float v) {
    return v * __builtin_amdgcn_rcpf(1.0f + __expf(-v));
}

// sigma: D-frag register order -> k feature. s = 32ks + 8q + i.
__device__ __forceinline__ int sigma_k(int s) {
    const int ks = s >> 5, qq = (s >> 3) & 3, i = s & 7;
    return 16 * (2 * ks + (i >> 2)) + 4 * qq + (i & 3);
}

// ============ prep: fp32 src[K][N] block -> f16 granule [n][slot ^ ((n&7)<<3)] ============
template<bool SIG>
__device__ void conv_blk(const float* __restrict__ src, f16* __restrict__ dst,
                         int srcN, int k0, int n0, int KB, int NB, int tid, int nth) {
    for (int idx = tid; idx < KB * NB; idx += nth) {
        const int s = idx / NB, nn = idx - s * NB;      // s = logical k-slot
        const int k = SIG ? sigma_k(s) : s;
        dst[nn * KB + (s ^ ((nn & 7) << 3))] = (f16)src[(long)(k0 + k) * srcN + n0 + nn];
    }
}

__global__ void prep_weights(const float* __restrict__ w1, const float* __restrict__ w2,
                             const float* __restrict__ gw1, const float* __restrict__ ew1,
                             const float* __restrict__ ew2, const float* __restrict__ sw,
                             const float* __restrict__ hw1, f16* __restrict__ ws) {
    const int tid = blockIdx.x * 256 + threadIdx.x;
    const int nth = gridDim.x * 256;
    for (int kq = 0; kq < 4; ++kq)
        for (int nh = 0; nh < 2; ++nh)
            conv_blk<false>(w1, ws + IMG_W1 + (kq * 2 + nh) * 4096, 128, kq * 64, nh * 64, 64, 64, tid, nth);
    for (int kh = 0; kh < 2; ++kh)
        conv_blk<true>(w2, ws + IMG_W2 + kh * 4096, 64, kh * 64, 0, 64, 64, tid, nth);
    conv_blk<true>(gw1, ws + IMG_GW1, 32, 0, 0, 64, 32, tid, nth);
    for (int e = 0; e < 4; ++e)
        for (int h = 0; h < 2; ++h) {
            conv_blk<true>(ew1 + e * 8192, ws + IMG_E + e * 16384 + h * 8192,        128, 0, h * 64, 64, 64, tid, nth);
            conv_blk<true>(ew2 + e * 8192, ws + IMG_E + e * 16384 + h * 8192 + 4096,  64, h * 64, 0, 64, 64, tid, nth);
        }
    conv_blk<true>(sw, ws + IMG_SWH, 64, 0, 0, 64, 64, tid, nth);
    for (int h = 0; h < 3; ++h)
        conv_blk<true>(hw1 + h * 2048, ws + IMG_SWH + 4096 + h * 2048, 32, 0, 0, 64, 32, tid, nth);
}

// ============ async global->LDS staging: 1KB chunks round-robined over 4 waves ============
template<int BYTES>
__device__ __forceinline__ void stage4(const f16* __restrict__ g, as3char* l, int wv, int lane) {
    constexpr int CH = BYTES / 1024;
    #pragma unroll
    for (int ch = 0; ch < CH; ++ch)
        if ((ch & 3) == wv)
            __builtin_amdgcn_global_load_lds(
                (const __attribute__((address_space(1))) void*)((const char*)g + ch * 1024 + lane * 16),
                (__attribute__((address_space(3))) void*)(l + ch * 1024), 16, 0, 0);
}

// ============ weight A-frag from swizzled LDS granule ============
__device__ __forceinline__ int swzW(int n) { return (n & 7) << 3; }

__device__ __forceinline__ f16x8 ldW(const f16* base, int row_base, int k0, int lane) {
    const int r = row_base + (lane & 15);
    const int k = k0 + ((lane >> 4) << 3);
    return *(const f16x8*)(base + r * 64 + (k ^ swzW(r)));
}

// NT n-tiles: acc[n] += W(A) x act(B)
template<int NT>
__device__ __forceinline__ void mmN(const f16x8 bf[2], const f16* wb, f32x4* acc, int lane) {
    #pragma unroll
    for (int ks = 0; ks < 2; ++ks)
        #pragma unroll
        for (int n = 0; n < NT; ++n) {
            const f16x8 w = ldW(wb, n * 16, ks * 32, lane);
            acc[n] = MFMA16(w, bf[ks], acc[n]);
        }
}

// D-acc (4 tiles) -> B-frags, register-only (order matches sigma)
__device__ __forceinline__ void silu_pack(const f32x4* a4, f16x8 bf[2]) {
    #pragma unroll
    for (int ks = 0; ks < 2; ++ks)
        #pragma unroll
        for (int i = 0; i < 8; ++i)
            bf[ks][i] = (f16)silu_f(a4[2 * ks + (i >> 2)][i & 3]);
}
__device__ __forceinline__ void pack_raw(const f32x4* a4, f16x8 bf[2]) {
    #pragma unroll
    for (int ks = 0; ks < 2; ++ks)
        #pragma unroll
        for (int i = 0; i < 8; ++i)
            bf[ks][i] = (f16)a4[2 * ks + (i >> 2)][i & 3];
}

__device__ __forceinline__ f16x8 cvt8(float4 a, float4 b) {
    f16x8 r;
    r[0] = (f16)a.x; r[1] = (f16)a.y; r[2] = (f16)a.z; r[3] = (f16)a.w;
    r[4] = (f16)b.x; r[5] = (f16)b.y; r[6] = (f16)b.z; r[7] = (f16)b.w;
    return r;
}

// sum across the 4 quad lanes {j, j+16, j+32, j+48}
__device__ __forceinline__ float qreduce(float v) {
    v += __shfl_xor(v, 16, 64);
    v += __shfl_xor(v, 32, 64);
    return v;
}

__global__ __launch_bounds__(256, 5)
void fused_net_mfma(const float* __restrict__ x,   const f16* __restrict__ wsp,
                    const float* __restrict__ b1,  const float* __restrict__ lng,
                    const float* __restrict__ lnb, const float* __restrict__ b2,
                    const float* __restrict__ eb1, const float* __restrict__ eb2,
                    const float* __restrict__ gb1, const float* __restrict__ gw2,
                    const float* __restrict__ gb2, const float* __restrict__ sb,
                    const float* __restrict__ hb1, const float* __restrict__ hw2,
                    const float* __restrict__ hb2, float* __restrict__ out)
{
    // 20 KB LDS: WA 8K | WB 8K | G 4K. No activation LDS at all.
    __shared__ __align__(16) f16 lds[10240];
    as3char* const LB = (as3char*)lds;
    const int lane = threadIdx.x & 63;
    const int wv   = threadIdx.x >> 6;
    const int j    = lane & 15;           // batch row within wave tile
    const int q    = lane >> 4;           // quad index (feature group)
    const int q4   = q * 4;
    f16* const WA = lds;          as3char* const WA_3 = LB;
    f16* const WB = lds + 4096;   as3char* const WB_3 = LB + 8192;
    f16* const G  = lds + 8192;   as3char* const G_3  = LB + 16384;

    const long row0 = (long)blockIdx.x * 64 + wv * 16;
    const float* xrow = x + (row0 + j) * 256 + q * 8;

    // ---- prologue: w1 g0 -> WA, gw1 -> G; x quarter 0 -> regs ----
    stage4<8192>(wsp + IMG_W1, WA_3, wv, lane);
    stage4<4096>(wsp + IMG_GW1, G_3, wv, lane);
    float4 xr[4];
    xr[0] = *(const float4*)(xrow);      xr[1] = *(const float4*)(xrow + 4);
    xr[2] = *(const float4*)(xrow + 32); xr[3] = *(const float4*)(xrow + 36);
    __syncthreads();

    // ================= stem1: 8 pipelined granule phases =================
    f32x4 acc[8];
    #pragma unroll
    for (int t = 0; t < 8; ++t)
        #pragma unroll
        for (int g = 0; g < 4; ++g) acc[t][g] = b1[t * 16 + q4 + g];

    #pragma unroll 1
    for (int kq = 0; kq < 4; ++kq) {
        const f16* curA = (kq & 1) ? WB : WA;
        as3char* othA   = (kq & 1) ? WA_3 : WB_3;
        const f16* curB = (kq & 1) ? WA : WB;
        as3char* othB   = (kq & 1) ? WB_3 : WA_3;

        // phase 2kq (cur: w1(kq,nh0)): stage w1(kq,nh1)
        stage4<8192>(wsp + IMG_W1 + (kq * 2 + 1) * 4096, othA, wv, lane);
        f16x8 af[2];
        af[0] = cvt8(xr[0], xr[1]);
        af[1] = cvt8(xr[2], xr[3]);
        mmN<4>(af, curA, acc, lane);
        __syncthreads();

        // phase 2kq+1 (cur: w1(kq,nh1)): stage next
        if (kq < 3) stage4<8192>(wsp + IMG_W1 + (kq + 1) * 2 * 4096, othB, wv, lane);
        else        stage4<8192>(wsp + IMG_W2, othB, wv, lane);
        if (kq < 3) {
            const float* xb = xrow + (kq + 1) * 64;
            xr[0] = *(const float4*)(xb);      xr[1] = *(const float4*)(xb + 4);
            xr[2] = *(const float4*)(xb + 32); xr[3] = *(const float4*)(xb + 36);
        }
        mmN<4>(af, curB, acc + 4, lane);
        __syncthreads();
    }

    // ---- LN stats: per-lane partial + 2-shfl quad reduce ----
    float s = 0.f, ss = 0.f;
    #pragma unroll
    for (int t = 0; t < 8; ++t)
        #pragma unroll
        for (int g = 0; g < 4; ++g) { const float v = acc[t][g]; s += v; ss += v * v; }
    s = qreduce(s); ss = qreduce(ss);
    const float mu  = s * 0.0078125f;
    const float rsv = rsqrtf(ss * 0.0078125f - mu * mu + 1e-5f);

    // ================= phase 8 (WA: w2 kh0): stage w2kh1 -> WB =================
    f32x4 a2[4];
    #pragma unroll
    for (int t = 0; t < 4; ++t)
        #pragma unroll
        for (int g = 0; g < 4; ++g) a2[t][g] = b2[t * 16 + q4 + g];
    stage4<8192>(wsp + IMG_W2 + 4096, WB_3, wv, lane);
    {
        f16x8 bf[2];
        #pragma unroll
        for (int ks = 0; ks < 2; ++ks)
            #pragma unroll
            for (int i = 0; i < 8; ++i) {
                const int t = 2 * ks + (i >> 2), g = i & 3, f = 16 * t + q4 + g;
                bf[ks][i] = (f16)silu_f((acc[t][g] - mu) * rsv * lng[f] + lnb[f]);
            }
        mmN<4>(bf, WA, a2, lane);
    }
    __syncthreads();

    // ================= phase 9 (WB: w2 kh1): stage e0 ew1h0 -> WA; gate ===========
    stage4<8192>(wsp + IMG_E, WA_3, wv, lane);
    f16x8 hbB[2];
    f32x4 gwt;
    {
        f16x8 bf[2];
        #pragma unroll
        for (int ks = 0; ks < 2; ++ks)
            #pragma unroll
            for (int i = 0; i < 8; ++i) {
                const int t = 4 + 2 * ks + (i >> 2), g = i & 3, f = 16 * t + q4 + g;
                bf[ks][i] = (f16)silu_f((acc[t][g] - mu) * rsv * lng[f] + lnb[f]);
            }
        mmN<4>(bf, WB, a2, lane);
        silu_pack(a2, hbB);

        // gate: N=32 (2 tiles), all in-register
        f32x4 ag[2];
        #pragma unroll
        for (int t = 0; t < 2; ++t)
            #pragma unroll
            for (int g = 0; g < 4; ++g) ag[t][g] = gb1[t * 16 + q4 + g];
        mmN<2>(hbB, G, ag, lane);
        f32x4 pg = {0, 0, 0, 0};
        #pragma unroll
        for (int t = 0; t < 2; ++t)
            #pragma unroll
            for (int g = 0; g < 4; ++g) {
                const int f = 16 * t + q4 + g;
                const f32x4 w4 = *(const f32x4*)(gw2 + f * 4);
                pg += silu_f(ag[t][g]) * w4;
            }
        #pragma unroll
        for (int o = 0; o < 4; ++o) pg[o] = qreduce(pg[o]);
        const f32x4 l = pg + *(const f32x4*)gb2;
        const float mx = fmaxf(fmaxf(l[0], l[1]), fmaxf(l[2], l[3]));
        f32x4 ee;
        #pragma unroll
        for (int o = 0; o < 4; ++o) ee[o] = __expf(l[o] - mx);
        gwt = ee * __builtin_amdgcn_rcpf(ee[0] + ee[1] + ee[2] + ee[3]);
    }
    __syncthreads();   // e0 ew1h0 ready in WA

    // ================= 4 experts: 4 pipelined phases each =================
    f32x4 moe[4] = {{0,0,0,0},{0,0,0,0},{0,0,0,0},{0,0,0,0}};
    #pragma unroll 1
    for (int e = 0; e < 4; ++e) {
        const f16* ebase = wsp + IMG_E + e * 16384;
        f32x4 a2e[4];
        #pragma unroll
        for (int t = 0; t < 4; ++t)
            #pragma unroll
            for (int g = 0; g < 4; ++g) a2e[t][g] = eb2[e * 64 + t * 16 + q4 + g];
        f16x8 eaB[2];
        // --- A (WA: ew1 h0): stage ew2h0 -> WB ---
        stage4<8192>(ebase + 4096 * 2, WB_3, wv, lane);   // note: +8192 B = +4096 f16
        {
            f32x4 aa[4];
            #pragma unroll
            for (int t = 0; t < 4; ++t)
                #pragma unroll
                for (int g = 0; g < 4; ++g) aa[t][g] = eb1[e * 128 + t * 16 + q4 + g];
            mmN<4>(hbB, WA, aa, lane);
            silu_pack(aa, eaB);
        }
        __syncthreads();
        // --- B (WB: ew2 h0): stage ew1h1 -> WA ---
        stage4<8192>(ebase + 8192, WA_3, wv, lane);
        mmN<4>(eaB, WB, a2e, lane);
        __syncthreads();
        // --- C (WA: ew1 h1): stage ew2h1 -> WB ---
        stage4<8192>(ebase + 8192 + 4096, WB_3, wv, lane);
        {
            f32x4 aa[4];
            #pragma unroll
            for (int t = 0; t < 4; ++t)
                #pragma unroll
                for (int g = 0; g < 4; ++g) aa[t][g] = eb1[e * 128 + 64 + t * 16 + q4 + g];
            mmN<4>(hbB, WA, aa, lane);
            silu_pack(aa, eaB);
        }
        __syncthreads();
        // --- D (WB: ew2 h1): stage next ew1h0 (or sw) -> WA ---
        if (e < 3) stage4<8192>(wsp + IMG_E + (e + 1) * 16384, WA_3, wv, lane);
        else       stage4<8192>(wsp + IMG_SWH, WA_3, wv, lane);
        mmN<4>(eaB, WB, a2e, lane);
        const float ge = (e == 0) ? gwt[0] : (e == 1) ? gwt[1] : (e == 2) ? gwt[2] : gwt[3];
        #pragma unroll
        for (int t = 0; t < 4; ++t)
            #pragma unroll
            for (int g = 0; g < 4; ++g)
                moe[t][g] += silu_f(a2e[t][g]) * ge;
        __syncthreads();
    }

    // ================= feat (WA: sw): stage hw1[0,1] -> WB, hw1[2] -> G ============
    stage4<8192>(wsp + IMG_SWH + 4096, WB_3, wv, lane);
    stage4<4096>(wsp + IMG_SWH + 8192, G_3, wv, lane);
    f16x8 featB[2];
    {
        f16x8 moeB[2];
        pack_raw(moe, moeB);
        f32x4 fs[4];
        #pragma unroll
        for (int t = 0; t < 4; ++t)
            #pragma unroll
            for (int g = 0; g < 4; ++g) fs[t][g] = sb[t * 16 + q4 + g];
        mmN<4>(moeB, WA, fs, lane);
        silu_pack(fs, featB);
    }
    __syncthreads();   // hw1[0,1] in WB, hw1[2] in G

    // ================= heads (WB: hw1[0]@0, hw1[1]@2048; G: hw1[2]) ================
    #pragma unroll
    for (int h = 0; h < 3; ++h) {
        const f16* hw = (h == 0) ? WB : (h == 1) ? (WB + 2048) : G;
        f32x4 ah[2];
        #pragma unroll
        for (int t = 0; t < 2; ++t)
            #pragma unroll
            for (int g = 0; g < 4; ++g) ah[t][g] = hb1[h * 32 + t * 16 + q4 + g];
        mmN<2>(featB, hw, ah, lane);
        float ph = 0.f;
        #pragma unroll
        for (int t = 0; t < 2; ++t)
            #pragma unroll
            for (int g = 0; g < 4; ++g)
                ph += silu_f(ah[t][g]) * hw2[h * 32 + t * 16 + q4 + g];
        ph = qreduce(ph);
        if (q == h) out[(row0 + j) * 3 + h] = ph + hb2[h];
    }
}

extern "C" void kernel_launch(void* const* d_in, const int* in_sizes, int n_in,
                              void* d_out, int out_size, void* d_ws, size_t ws_size,
                              hipStream_t stream) {
    const float* x    = (const float*)d_in[0];
    const float* w1   = (const float*)d_in[1];
    const float* b1   = (const float*)d_in[2];
    const float* lng  = (const float*)d_in[3];
    const float* lnb  = (const float*)d_in[4];
    const float* w2   = (const float*)d_in[5];
    const float* b2   = (const float*)d_in[6];
    const float* ew1  = (const float*)d_in[7];
    const float* eb1  = (const float*)d_in[8];
    const float* ew2  = (const float*)d_in[9];
    const float* eb2  = (const float*)d_in[10];
    const float* gw1  = (const float*)d_in[11];
    const float* gb1  = (const float*)d_in[12];
    const float* gw2  = (const float*)d_in[13];
    const float* gb2  = (const float*)d_in[14];
    const float* sw   = (const float*)d_in[15];
    const float* sb   = (const float*)d_in[16];
    const float* hw1  = (const float*)d_in[17];
    const float* hb1  = (const float*)d_in[18];
    const float* hw2  = (const float*)d_in[19];
    const float* hb2  = (const float*)d_in[20];
    float* out = (float*)d_out;
    f16* ws = (f16*)d_ws;

    hipLaunchKernelGGL(prep_weights, dim3(64), dim3(256), 0, stream,
                       w1, w2, gw1, ew1, ew2, sw, hw1, ws);

    const int B = in_sizes[0] / 256;
    const int grid = B / 64;
    hipLaunchKernelGGL(fused_net_mfma, dim3(grid), dim3(256), 0, stream,
                       x, ws, b1, lng, lnb, b2, eb1, eb2, gb1, gw2, gb2,
                       sb, hb1, hw2, hb2, out);
}